// Round 1
// baseline (662.622 us; speedup 1.0000x reference)
//
#include <hip/hip_runtime.h>

#define CC 128
#define TN 32

__device__ __forceinline__ float enc_nan(float v) {
    if (v != v) return 0.f;
    if (v > 3.0e38f) return 1.f;
    if (v < -3.0e38f) return -1.f;
    return v;
}

__device__ __forceinline__ void atomAddF(float* p, float v) {
#if defined(__AMDGCN__) || defined(__HIP_DEVICE_COMPILE__)
    unsafeAtomicAdd(p, v);
#else
    atomicAdd(p, v);
#endif
}

__global__ __launch_bounds__(256)
void k_init(const float4* __restrict__ xin, float4* __restrict__ xout, int n4) {
    int i = blockIdx.x * 256 + threadIdx.x;
    if (i < n4) {
        float4 v = xin[i];
        v.x = enc_nan(v.x); v.y = enc_nan(v.y); v.z = enc_nan(v.z); v.w = enc_nan(v.w);
        xout[i] = v;
    }
}

// pred[node] = relu(x[node] @ w1 + b1) @ w2 + b2
__global__ __launch_bounds__(256)
void k_pred(const float* __restrict__ x, float* __restrict__ pred, int N,
            const float* __restrict__ w1, const float* __restrict__ b1,
            const float* __restrict__ w2, const float* __restrict__ b2)
{
    __shared__ float xs[TN][CC];
    __shared__ float hs[TN][CC];
    const int tid = threadIdx.x;
    const int base = blockIdx.x * TN;

    for (int i = tid; i < TN * CC / 4; i += 256) {
        int n = i >> 5;
        int c = (i & 31) << 2;
        int node = base + n;
        float4 v = make_float4(0.f, 0.f, 0.f, 0.f);
        if (node < N) v = *reinterpret_cast<const float4*>(x + (size_t)node * CC + c);
        *reinterpret_cast<float4*>(&xs[n][c]) = v;
    }
    __syncthreads();

    const int tn = tid >> 5;       // node group 0..7  -> nodes tn*4..tn*4+3
    const int tc = tid & 31;       // chan group 0..31 -> chans tc*4..tc*4+3
    const int c0 = tc * 4, n0 = tn * 4;

    float acc[4][4];
    #pragma unroll
    for (int i = 0; i < 4; ++i)
        #pragma unroll
        for (int j = 0; j < 4; ++j) acc[i][j] = 0.f;

    for (int k = 0; k < CC; k += 4) {
        float4 xv[4];
        #pragma unroll
        for (int i = 0; i < 4; ++i) xv[i] = *reinterpret_cast<const float4*>(&xs[n0 + i][k]);
        #pragma unroll
        for (int kk = 0; kk < 4; ++kk) {
            float4 wv = *reinterpret_cast<const float4*>(w1 + (size_t)(k + kk) * CC + c0);
            #pragma unroll
            for (int i = 0; i < 4; ++i) {
                float xk = (kk == 0) ? xv[i].x : (kk == 1) ? xv[i].y : (kk == 2) ? xv[i].z : xv[i].w;
                acc[i][0] = fmaf(xk, wv.x, acc[i][0]);
                acc[i][1] = fmaf(xk, wv.y, acc[i][1]);
                acc[i][2] = fmaf(xk, wv.z, acc[i][2]);
                acc[i][3] = fmaf(xk, wv.w, acc[i][3]);
            }
        }
    }
    {
        float4 bv = *reinterpret_cast<const float4*>(b1 + c0);
        #pragma unroll
        for (int i = 0; i < 4; ++i) {
            float4 h;
            h.x = fmaxf(acc[i][0] + bv.x, 0.f);
            h.y = fmaxf(acc[i][1] + bv.y, 0.f);
            h.z = fmaxf(acc[i][2] + bv.z, 0.f);
            h.w = fmaxf(acc[i][3] + bv.w, 0.f);
            *reinterpret_cast<float4*>(&hs[n0 + i][c0]) = h;
        }
    }
    __syncthreads();

    #pragma unroll
    for (int i = 0; i < 4; ++i)
        #pragma unroll
        for (int j = 0; j < 4; ++j) acc[i][j] = 0.f;

    for (int k = 0; k < CC; k += 4) {
        float4 xv[4];
        #pragma unroll
        for (int i = 0; i < 4; ++i) xv[i] = *reinterpret_cast<const float4*>(&hs[n0 + i][k]);
        #pragma unroll
        for (int kk = 0; kk < 4; ++kk) {
            float4 wv = *reinterpret_cast<const float4*>(w2 + (size_t)(k + kk) * CC + c0);
            #pragma unroll
            for (int i = 0; i < 4; ++i) {
                float xk = (kk == 0) ? xv[i].x : (kk == 1) ? xv[i].y : (kk == 2) ? xv[i].z : xv[i].w;
                acc[i][0] = fmaf(xk, wv.x, acc[i][0]);
                acc[i][1] = fmaf(xk, wv.y, acc[i][1]);
                acc[i][2] = fmaf(xk, wv.z, acc[i][2]);
                acc[i][3] = fmaf(xk, wv.w, acc[i][3]);
            }
        }
    }
    {
        float4 bv = *reinterpret_cast<const float4*>(b2 + c0);
        #pragma unroll
        for (int i = 0; i < 4; ++i) {
            int node = base + n0 + i;
            if (node < N) {
                float4 o;
                o.x = acc[i][0] + bv.x;
                o.y = acc[i][1] + bv.y;
                o.z = acc[i][2] + bv.z;
                o.w = acc[i][3] + bv.w;
                *reinterpret_cast<float4*>(pred + (size_t)node * CC + c0) = o;
            }
        }
    }
}

// one wave per edge: msg = LN(x_src[src] - pred[dst]) * g + be ; atomic mean-accumulate
__global__ __launch_bounds__(256)
void k_edge(const int* __restrict__ esrc, const int* __restrict__ edst, int E,
            const float* __restrict__ xsrc, const float* __restrict__ pred,
            const float* __restrict__ g, const float* __restrict__ be,
            float* __restrict__ agg, float* __restrict__ cnt)
{
    int e = blockIdx.x * 4 + (threadIdx.x >> 6);
    int lane = threadIdx.x & 63;
    if (e >= E) return;
    int s = esrc[e], d = edst[e];
    const float* xj = xsrc + (size_t)s * CC;
    const float* pr = pred + (size_t)d * CC;
    float d0 = xj[lane] - pr[lane];
    float d1 = xj[lane + 64] - pr[lane + 64];
    float s1 = d0 + d1;
    float s2 = fmaf(d0, d0, d1 * d1);
    #pragma unroll
    for (int m = 1; m < 64; m <<= 1) { s1 += __shfl_xor(s1, m); s2 += __shfl_xor(s2, m); }
    float mean = s1 * (1.f / 128.f);
    float var = s2 * (1.f / 128.f) - mean * mean;
    float r = rsqrtf(var + 1e-5f);
    float m0 = fmaf((d0 - mean) * r, g[lane], be[lane]);
    float m1 = fmaf((d1 - mean) * r, g[lane + 64], be[lane + 64]);
    atomAddF(&agg[(size_t)d * CC + lane], m0);
    atomAddF(&agg[(size_t)d * CC + lane + 64], m1);
    if (lane == 0) atomAddF(&cnt[d], 1.f);
}

// x_next = relu(LN(relu(concat(x_dst, agg/max(cnt,1)) @ uw + ub)))
__global__ __launch_bounds__(256)
void k_update(const float* __restrict__ xdst, const float* __restrict__ agg,
              const float* __restrict__ cnt, float* __restrict__ xnext, int N,
              const float* __restrict__ uw, const float* __restrict__ ub,
              const float* __restrict__ ng, const float* __restrict__ nb)
{
    __shared__ float us[TN][2 * CC];      // concat input tile
    __shared__ float os[TN][CC + 4];      // update output tile (padded stride 132 -> LN reads conflict-free)
    const int tid = threadIdx.x;
    const int base = blockIdx.x * TN;

    for (int i = tid; i < TN * CC / 4; i += 256) {
        int n = i >> 5;
        int c = (i & 31) << 2;
        int node = base + n;
        float4 xv = make_float4(0.f, 0.f, 0.f, 0.f);
        float4 av = xv;
        if (node < N) {
            xv = *reinterpret_cast<const float4*>(xdst + (size_t)node * CC + c);
            float ic = 1.f / fmaxf(cnt[node], 1.f);
            float4 a = *reinterpret_cast<const float4*>(agg + (size_t)node * CC + c);
            av.x = a.x * ic; av.y = a.y * ic; av.z = a.z * ic; av.w = a.w * ic;
        }
        *reinterpret_cast<float4*>(&us[n][c]) = xv;
        *reinterpret_cast<float4*>(&us[n][CC + c]) = av;
    }
    __syncthreads();

    const int tn = tid >> 5;
    const int tc = tid & 31;
    const int c0 = tc * 4, n0 = tn * 4;

    float acc[4][4];
    #pragma unroll
    for (int i = 0; i < 4; ++i)
        #pragma unroll
        for (int j = 0; j < 4; ++j) acc[i][j] = 0.f;

    for (int k = 0; k < 2 * CC; k += 4) {
        float4 xv[4];
        #pragma unroll
        for (int i = 0; i < 4; ++i) xv[i] = *reinterpret_cast<const float4*>(&us[n0 + i][k]);
        #pragma unroll
        for (int kk = 0; kk < 4; ++kk) {
            float4 wv = *reinterpret_cast<const float4*>(uw + (size_t)(k + kk) * CC + c0);
            #pragma unroll
            for (int i = 0; i < 4; ++i) {
                float xk = (kk == 0) ? xv[i].x : (kk == 1) ? xv[i].y : (kk == 2) ? xv[i].z : xv[i].w;
                acc[i][0] = fmaf(xk, wv.x, acc[i][0]);
                acc[i][1] = fmaf(xk, wv.y, acc[i][1]);
                acc[i][2] = fmaf(xk, wv.z, acc[i][2]);
                acc[i][3] = fmaf(xk, wv.w, acc[i][3]);
            }
        }
    }
    {
        float4 bv = *reinterpret_cast<const float4*>(ub + c0);
        #pragma unroll
        for (int i = 0; i < 4; ++i) {
            float4 o;
            o.x = fmaxf(acc[i][0] + bv.x, 0.f);
            o.y = fmaxf(acc[i][1] + bv.y, 0.f);
            o.z = fmaxf(acc[i][2] + bv.z, 0.f);
            o.w = fmaxf(acc[i][3] + bv.w, 0.f);
            *reinterpret_cast<float4*>(&os[n0 + i][c0]) = o;
        }
    }
    __syncthreads();

    // node LayerNorm + relu; 8 lanes per node, 16 channels per lane
    const int wv_ = tid >> 6;
    const int lane = tid & 63;
    const int nl = wv_ * 8 + (lane >> 3);
    const int cl = lane & 7;
    float vals[16];
    float sm = 0.f, sq = 0.f;
    #pragma unroll
    for (int t = 0; t < 16; ++t) {
        float u = os[nl][cl + 8 * t];
        vals[t] = u; sm += u; sq = fmaf(u, u, sq);
    }
    #pragma unroll
    for (int m = 1; m < 8; m <<= 1) { sm += __shfl_xor(sm, m); sq += __shfl_xor(sq, m); }
    float mean = sm * (1.f / 128.f);
    float var = sq * (1.f / 128.f) - mean * mean;
    float r = rsqrtf(var + 1e-5f);
    int node = base + nl;
    if (node < N) {
        #pragma unroll
        for (int t = 0; t < 16; ++t) {
            int c = cl + 8 * t;
            float o = fmaxf(fmaf((vals[t] - mean) * r, ng[c], nb[c]), 0.f);
            xnext[(size_t)node * CC + c] = o;
        }
    }
}

__global__ __launch_bounds__(256)
void k_head(const float* __restrict__ xa, const float* __restrict__ hw,
            const float* __restrict__ hb, float* __restrict__ out, int S)
{
    int w = blockIdx.x * 4 + (threadIdx.x >> 6);
    int lane = threadIdx.x & 63;
    if (w >= S) return;
    float v = fmaf(xa[(size_t)w * CC + lane], hw[lane],
                   xa[(size_t)w * CC + lane + 64] * hw[lane + 64]);
    #pragma unroll
    for (int m = 1; m < 64; m <<= 1) v += __shfl_xor(v, m);
    if (lane == 0) out[w] = v + hb[0];
}

extern "C" void kernel_launch(void* const* d_in, const int* in_sizes, int n_in,
                              void* d_out, int out_size, void* d_ws, size_t ws_size,
                              hipStream_t stream)
{
    const float* x_a_in = (const float*)d_in[0];
    const float* x_b_in = (const float*)d_in[1];
    const int*   e_ab   = (const int*)d_in[2];
    const int*   e_ba   = (const int*)d_in[3];
    const float* pw1    = (const float*)d_in[4];
    const float* pb1    = (const float*)d_in[5];
    const float* pw2    = (const float*)d_in[6];
    const float* pb2    = (const float*)d_in[7];
    const float* mgam   = (const float*)d_in[8];
    const float* mbet   = (const float*)d_in[9];
    const float* uw     = (const float*)d_in[10];
    const float* ubias  = (const float*)d_in[11];
    const float* ngam   = (const float*)d_in[12];
    const float* nbet   = (const float*)d_in[13];
    const float* hw     = (const float*)d_in[14];
    const float* hb     = (const float*)d_in[15];

    const int NA  = in_sizes[0] / CC;
    const int NB  = in_sizes[1] / CC;
    const int Eab = in_sizes[2] / 2;
    const int Eba = in_sizes[3] / 2;
    const int NMAX = NA > NB ? NA : NB;

    float* ws = (float*)d_ws;
    size_t off = 0;
    float* xa0   = ws + off; off += (size_t)NA * CC;
    float* xa1   = ws + off; off += (size_t)NA * CC;
    float* xb0   = ws + off; off += (size_t)NB * CC;
    float* xb1   = ws + off; off += (size_t)NB * CC;
    float* prd   = ws + off; off += (size_t)NMAX * CC;
    float* agg_a = ws + off; off += (size_t)NA * CC;
    float* agg_b = ws + off; off += (size_t)NB * CC;
    float* cnt_a = ws + off; off += (size_t)NA;
    float* cnt_b = ws + off; off += (size_t)NB;

    k_init<<<dim3((NA * CC / 4 + 255) / 256), dim3(256), 0, stream>>>(
        (const float4*)x_a_in, (float4*)xa0, NA * CC / 4);
    k_init<<<dim3((NB * CC / 4 + 255) / 256), dim3(256), 0, stream>>>(
        (const float4*)x_b_in, (float4*)xb0, NB * CC / 4);

    float* xa_cur = xa0; float* xa_nxt = xa1;
    float* xb_cur = xb0; float* xb_nxt = xb1;

    for (int l = 0; l < 2; ++l) {
        int t0 = l * 2 + 0;   // conv a->b (dst = b)
        int t1 = l * 2 + 1;   // conv b->a (dst = a)

        k_pred<<<dim3((NB + TN - 1) / TN), dim3(256), 0, stream>>>(
            xb_cur, prd, NB, pw1 + (size_t)t0 * CC * CC, pb1 + t0 * CC,
            pw2 + (size_t)t0 * CC * CC, pb2 + t0 * CC);
        hipMemsetAsync(agg_b, 0, (size_t)NB * CC * sizeof(float), stream);
        hipMemsetAsync(cnt_b, 0, (size_t)NB * sizeof(float), stream);
        k_edge<<<dim3((Eab + 3) / 4), dim3(256), 0, stream>>>(
            e_ab, e_ab + Eab, Eab, xa_cur, prd,
            mgam + t0 * CC, mbet + t0 * CC, agg_b, cnt_b);

        k_pred<<<dim3((NA + TN - 1) / TN), dim3(256), 0, stream>>>(
            xa_cur, prd, NA, pw1 + (size_t)t1 * CC * CC, pb1 + t1 * CC,
            pw2 + (size_t)t1 * CC * CC, pb2 + t1 * CC);
        hipMemsetAsync(agg_a, 0, (size_t)NA * CC * sizeof(float), stream);
        hipMemsetAsync(cnt_a, 0, (size_t)NA * sizeof(float), stream);
        k_edge<<<dim3((Eba + 3) / 4), dim3(256), 0, stream>>>(
            e_ba, e_ba + Eba, Eba, xb_cur, prd,
            mgam + t1 * CC, mbet + t1 * CC, agg_a, cnt_a);

        k_update<<<dim3((NB + TN - 1) / TN), dim3(256), 0, stream>>>(
            xb_cur, agg_b, cnt_b, xb_nxt, NB,
            uw + (size_t)t0 * 2 * CC * CC, ubias + t0 * CC,
            ngam + t0 * CC, nbet + t0 * CC);
        k_update<<<dim3((NA + TN - 1) / TN), dim3(256), 0, stream>>>(
            xa_cur, agg_a, cnt_a, xa_nxt, NA,
            uw + (size_t)t1 * 2 * CC * CC, ubias + t1 * CC,
            ngam + t1 * CC, nbet + t1 * CC);

        float* t;
        t = xa_cur; xa_cur = xa_nxt; xa_nxt = t;
        t = xb_cur; xb_cur = xb_nxt; xb_nxt = t;
    }

    k_head<<<dim3((out_size + 3) / 4), dim3(256), 0, stream>>>(
        xa_cur, hw, hb, (float*)d_out, out_size);
}

// Round 2
// 562.358 us; speedup vs baseline: 1.1783x; 1.1783x over previous
//
#include <hip/hip_runtime.h>

#define CC 128
#define TN 32
#define SCAN_T 1024
#define SCAN_I 4

__device__ __forceinline__ float enc_nan(float v) {
    if (v != v) return 0.f;
    if (v > 3.0e38f) return 1.f;
    if (v < -3.0e38f) return -1.f;
    return v;
}

__global__ __launch_bounds__(256)
void k_init(const float4* __restrict__ xin, float4* __restrict__ xout, int n4) {
    int i = blockIdx.x * 256 + threadIdx.x;
    if (i < n4) {
        float4 v = xin[i];
        v.x = enc_nan(v.x); v.y = enc_nan(v.y); v.z = enc_nan(v.z); v.w = enc_nan(v.w);
        xout[i] = v;
    }
}

// ---------- CSR build ----------
__global__ __launch_bounds__(256)
void k_hist(const int* __restrict__ dst, int n, int* __restrict__ cnt) {
    int i = blockIdx.x * 256 + threadIdx.x;
    if (i < n) atomicAdd(&cnt[dst[i]], 1);
}

// single-block hierarchical exclusive scan; writes row_ptr[0..n] and off[0..n-1]
__global__ __launch_bounds__(SCAN_T)
void k_scan(const int* __restrict__ cnt, int* __restrict__ row_ptr,
            int* __restrict__ off, int n)
{
    __shared__ int wsum[SCAN_T / 64];
    __shared__ int carry_s;
    const int tid = threadIdx.x, lane = tid & 63, wid = tid >> 6;
    if (tid == 0) carry_s = 0;
    __syncthreads();
    const int chunk = SCAN_T * SCAN_I;
    for (int base = 0; base < n; base += chunk) {
        int i0 = base + tid * SCAN_I;
        int v[SCAN_I];
        int local = 0;
        #pragma unroll
        for (int t = 0; t < SCAN_I; ++t) {
            int i = i0 + t;
            v[t] = (i < n) ? cnt[i] : 0;
            local += v[t];
        }
        int incl = local;
        #pragma unroll
        for (int d = 1; d < 64; d <<= 1) {
            int t = __shfl_up(incl, d);
            if (lane >= d) incl += t;
        }
        if (lane == 63) wsum[wid] = incl;
        __syncthreads();
        if (wid == 0) {
            int wv = (lane < SCAN_T / 64) ? wsum[lane] : 0;
            int winc = wv;
            #pragma unroll
            for (int d = 1; d < SCAN_T / 64; d <<= 1) {
                int t = __shfl_up(winc, d);
                if (lane >= d) winc += t;
            }
            if (lane < SCAN_T / 64) wsum[lane] = winc - wv;  // exclusive wave offset
        }
        __syncthreads();
        int carry = carry_s;
        int excl = carry + wsum[wid] + incl - local;
        #pragma unroll
        for (int t = 0; t < SCAN_I; ++t) {
            int i = i0 + t;
            if (i < n) { row_ptr[i] = excl; off[i] = excl; }
            excl += v[t];
        }
        __syncthreads();
        if (tid == SCAN_T - 1) carry_s = carry + wsum[SCAN_T / 64 - 1] + incl;
        __syncthreads();
    }
    if (threadIdx.x == 0) row_ptr[n] = carry_s;
}

__global__ __launch_bounds__(256)
void k_scatter(const int* __restrict__ src, const int* __restrict__ dst, int n,
               int* __restrict__ off, int* __restrict__ srcs)
{
    int i = blockIdx.x * 256 + threadIdx.x;
    if (i < n) {
        int p = atomicAdd(&off[dst[i]], 1);
        srcs[p] = src[i];
    }
}

// ---------- node-level pred MLP: pred = relu(x @ w1 + b1) @ w2 + b2 ----------
__global__ __launch_bounds__(256)
void k_pred(const float* __restrict__ x, float* __restrict__ pred, int N,
            const float* __restrict__ w1, const float* __restrict__ b1,
            const float* __restrict__ w2, const float* __restrict__ b2)
{
    __shared__ float xs[TN][CC];
    __shared__ float hs[TN][CC];
    const int tid = threadIdx.x;
    const int base = blockIdx.x * TN;

    for (int i = tid; i < TN * CC / 4; i += 256) {
        int n = i >> 5;
        int c = (i & 31) << 2;
        int node = base + n;
        float4 v = make_float4(0.f, 0.f, 0.f, 0.f);
        if (node < N) v = *reinterpret_cast<const float4*>(x + (size_t)node * CC + c);
        *reinterpret_cast<float4*>(&xs[n][c]) = v;
    }
    __syncthreads();

    const int tn = tid >> 5;
    const int tc = tid & 31;
    const int c0 = tc * 4, n0 = tn * 4;

    float acc[4][4];
    #pragma unroll
    for (int i = 0; i < 4; ++i)
        #pragma unroll
        for (int j = 0; j < 4; ++j) acc[i][j] = 0.f;

    for (int k = 0; k < CC; k += 4) {
        float4 xv[4];
        #pragma unroll
        for (int i = 0; i < 4; ++i) xv[i] = *reinterpret_cast<const float4*>(&xs[n0 + i][k]);
        #pragma unroll
        for (int kk = 0; kk < 4; ++kk) {
            float4 wv = *reinterpret_cast<const float4*>(w1 + (size_t)(k + kk) * CC + c0);
            #pragma unroll
            for (int i = 0; i < 4; ++i) {
                float xk = (kk == 0) ? xv[i].x : (kk == 1) ? xv[i].y : (kk == 2) ? xv[i].z : xv[i].w;
                acc[i][0] = fmaf(xk, wv.x, acc[i][0]);
                acc[i][1] = fmaf(xk, wv.y, acc[i][1]);
                acc[i][2] = fmaf(xk, wv.z, acc[i][2]);
                acc[i][3] = fmaf(xk, wv.w, acc[i][3]);
            }
        }
    }
    {
        float4 bv = *reinterpret_cast<const float4*>(b1 + c0);
        #pragma unroll
        for (int i = 0; i < 4; ++i) {
            float4 h;
            h.x = fmaxf(acc[i][0] + bv.x, 0.f);
            h.y = fmaxf(acc[i][1] + bv.y, 0.f);
            h.z = fmaxf(acc[i][2] + bv.z, 0.f);
            h.w = fmaxf(acc[i][3] + bv.w, 0.f);
            *reinterpret_cast<float4*>(&hs[n0 + i][c0]) = h;
        }
    }
    __syncthreads();

    #pragma unroll
    for (int i = 0; i < 4; ++i)
        #pragma unroll
        for (int j = 0; j < 4; ++j) acc[i][j] = 0.f;

    for (int k = 0; k < CC; k += 4) {
        float4 xv[4];
        #pragma unroll
        for (int i = 0; i < 4; ++i) xv[i] = *reinterpret_cast<const float4*>(&hs[n0 + i][k]);
        #pragma unroll
        for (int kk = 0; kk < 4; ++kk) {
            float4 wv = *reinterpret_cast<const float4*>(w2 + (size_t)(k + kk) * CC + c0);
            #pragma unroll
            for (int i = 0; i < 4; ++i) {
                float xk = (kk == 0) ? xv[i].x : (kk == 1) ? xv[i].y : (kk == 2) ? xv[i].z : xv[i].w;
                acc[i][0] = fmaf(xk, wv.x, acc[i][0]);
                acc[i][1] = fmaf(xk, wv.y, acc[i][1]);
                acc[i][2] = fmaf(xk, wv.z, acc[i][2]);
                acc[i][3] = fmaf(xk, wv.w, acc[i][3]);
            }
        }
    }
    {
        float4 bv = *reinterpret_cast<const float4*>(b2 + c0);
        #pragma unroll
        for (int i = 0; i < 4; ++i) {
            int node = base + n0 + i;
            if (node < N) {
                float4 o;
                o.x = acc[i][0] + bv.x;
                o.y = acc[i][1] + bv.y;
                o.z = acc[i][2] + bv.z;
                o.w = acc[i][3] + bv.w;
                *reinterpret_cast<float4*>(pred + (size_t)node * CC + c0) = o;
            }
        }
    }
}

// ---------- gather-side aggregation: one wave per dst node ----------
// agg[d] = mean_e LN(x_src[srcs[e]] - pred[d]) * g + be   (0 if no edges)
__global__ __launch_bounds__(256)
void k_agg(const int* __restrict__ row_ptr, const int* __restrict__ srcs,
           const float* __restrict__ xsrc, const float* __restrict__ pred,
           const float* __restrict__ g, const float* __restrict__ be,
           float* __restrict__ agg, int N)
{
    int d = blockIdx.x * 4 + (threadIdx.x >> 6);
    int lane = threadIdx.x & 63;
    if (d >= N) return;
    int jb = row_ptr[d], je = row_ptr[d + 1];
    int deg = je - jb;
    const int c = lane * 2;
    float2 pr = *reinterpret_cast<const float2*>(pred + (size_t)d * CC + c);
    float g0 = g[c], g1 = g[c + 1], b0 = be[c], b1 = be[c + 1];
    float a0 = 0.f, a1 = 0.f;
    if (deg > 0) {
        float2 xj = *reinterpret_cast<const float2*>(xsrc + (size_t)srcs[jb] * CC + c);
        for (int j = jb; j < je; ++j) {
            float2 xn = xj;
            if (j + 1 < je)
                xn = *reinterpret_cast<const float2*>(xsrc + (size_t)srcs[j + 1] * CC + c);
            float d0 = xj.x - pr.x, d1 = xj.y - pr.y;
            float sm = d0 + d1, sq = fmaf(d0, d0, d1 * d1);
            #pragma unroll
            for (int m = 1; m < 64; m <<= 1) { sm += __shfl_xor(sm, m); sq += __shfl_xor(sq, m); }
            float mean = sm * (1.f / 128.f);
            float var = sq * (1.f / 128.f) - mean * mean;
            float r = rsqrtf(var + 1e-5f);
            a0 += fmaf((d0 - mean) * r, g0, b0);
            a1 += fmaf((d1 - mean) * r, g1, b1);
            xj = xn;
        }
        float inv = 1.f / (float)deg;
        a0 *= inv; a1 *= inv;
    }
    *reinterpret_cast<float2*>(agg + (size_t)d * CC + c) = make_float2(a0, a1);
}

// ---------- x = relu(LN(relu(concat(x, agg) @ uw + ub)))  (in-place safe) ----------
__global__ __launch_bounds__(256)
void k_update(const float* xdst, const float* __restrict__ agg,
              float* xnext, int N,
              const float* __restrict__ uw, const float* __restrict__ ub,
              const float* __restrict__ ng, const float* __restrict__ nb)
{
    __shared__ float us[TN][2 * CC];
    __shared__ float os[TN][CC + 4];
    const int tid = threadIdx.x;
    const int base = blockIdx.x * TN;

    for (int i = tid; i < TN * CC / 4; i += 256) {
        int n = i >> 5;
        int c = (i & 31) << 2;
        int node = base + n;
        float4 xv = make_float4(0.f, 0.f, 0.f, 0.f);
        float4 av = xv;
        if (node < N) {
            xv = *reinterpret_cast<const float4*>(xdst + (size_t)node * CC + c);
            av = *reinterpret_cast<const float4*>(agg + (size_t)node * CC + c);
        }
        *reinterpret_cast<float4*>(&us[n][c]) = xv;
        *reinterpret_cast<float4*>(&us[n][CC + c]) = av;
    }
    __syncthreads();

    const int tn = tid >> 5;
    const int tc = tid & 31;
    const int c0 = tc * 4, n0 = tn * 4;

    float acc[4][4];
    #pragma unroll
    for (int i = 0; i < 4; ++i)
        #pragma unroll
        for (int j = 0; j < 4; ++j) acc[i][j] = 0.f;

    for (int k = 0; k < 2 * CC; k += 4) {
        float4 xv[4];
        #pragma unroll
        for (int i = 0; i < 4; ++i) xv[i] = *reinterpret_cast<const float4*>(&us[n0 + i][k]);
        #pragma unroll
        for (int kk = 0; kk < 4; ++kk) {
            float4 wv = *reinterpret_cast<const float4*>(uw + (size_t)(k + kk) * CC + c0);
            #pragma unroll
            for (int i = 0; i < 4; ++i) {
                float xk = (kk == 0) ? xv[i].x : (kk == 1) ? xv[i].y : (kk == 2) ? xv[i].z : xv[i].w;
                acc[i][0] = fmaf(xk, wv.x, acc[i][0]);
                acc[i][1] = fmaf(xk, wv.y, acc[i][1]);
                acc[i][2] = fmaf(xk, wv.z, acc[i][2]);
                acc[i][3] = fmaf(xk, wv.w, acc[i][3]);
            }
        }
    }
    {
        float4 bv = *reinterpret_cast<const float4*>(ub + c0);
        #pragma unroll
        for (int i = 0; i < 4; ++i) {
            float4 o;
            o.x = fmaxf(acc[i][0] + bv.x, 0.f);
            o.y = fmaxf(acc[i][1] + bv.y, 0.f);
            o.z = fmaxf(acc[i][2] + bv.z, 0.f);
            o.w = fmaxf(acc[i][3] + bv.w, 0.f);
            *reinterpret_cast<float4*>(&os[n0 + i][c0]) = o;
        }
    }
    __syncthreads();

    const int wv_ = tid >> 6;
    const int lane = tid & 63;
    const int nl = wv_ * 8 + (lane >> 3);
    const int cl = lane & 7;
    float vals[16];
    float sm = 0.f, sq = 0.f;
    #pragma unroll
    for (int t = 0; t < 16; ++t) {
        float u = os[nl][cl + 8 * t];
        vals[t] = u; sm += u; sq = fmaf(u, u, sq);
    }
    #pragma unroll
    for (int m = 1; m < 8; m <<= 1) { sm += __shfl_xor(sm, m); sq += __shfl_xor(sq, m); }
    float mean = sm * (1.f / 128.f);
    float var = sq * (1.f / 128.f) - mean * mean;
    float r = rsqrtf(var + 1e-5f);
    int node = base + nl;
    if (node < N) {
        #pragma unroll
        for (int t = 0; t < 16; ++t) {
            int c = cl + 8 * t;
            float o = fmaxf(fmaf((vals[t] - mean) * r, ng[c], nb[c]), 0.f);
            xnext[(size_t)node * CC + c] = o;
        }
    }
}

__global__ __launch_bounds__(256)
void k_head(const float* __restrict__ xa, const float* __restrict__ hw,
            const float* __restrict__ hb, float* __restrict__ out, int S)
{
    int w = blockIdx.x * 4 + (threadIdx.x >> 6);
    int lane = threadIdx.x & 63;
    if (w >= S) return;
    float v = fmaf(xa[(size_t)w * CC + lane], hw[lane],
                   xa[(size_t)w * CC + lane + 64] * hw[lane + 64]);
    #pragma unroll
    for (int m = 1; m < 64; m <<= 1) v += __shfl_xor(v, m);
    if (lane == 0) out[w] = v + hb[0];
}

extern "C" void kernel_launch(void* const* d_in, const int* in_sizes, int n_in,
                              void* d_out, int out_size, void* d_ws, size_t ws_size,
                              hipStream_t stream)
{
    const float* x_a_in = (const float*)d_in[0];
    const float* x_b_in = (const float*)d_in[1];
    const int*   e_ab   = (const int*)d_in[2];
    const int*   e_ba   = (const int*)d_in[3];
    const float* pw1    = (const float*)d_in[4];
    const float* pb1    = (const float*)d_in[5];
    const float* pw2    = (const float*)d_in[6];
    const float* pb2    = (const float*)d_in[7];
    const float* mgam   = (const float*)d_in[8];
    const float* mbet   = (const float*)d_in[9];
    const float* uw     = (const float*)d_in[10];
    const float* ubias  = (const float*)d_in[11];
    const float* ngam   = (const float*)d_in[12];
    const float* nbet   = (const float*)d_in[13];
    const float* hw     = (const float*)d_in[14];
    const float* hb     = (const float*)d_in[15];

    const int NA  = in_sizes[0] / CC;
    const int NB  = in_sizes[1] / CC;
    const int Eab = in_sizes[2] / 2;
    const int Eba = in_sizes[3] / 2;
    const int NMAX = NA > NB ? NA : NB;

    float* ws = (float*)d_ws;
    size_t off = 0;
    float* xa    = ws + off; off += (size_t)NA * CC;
    float* xb    = ws + off; off += (size_t)NB * CC;
    float* prd   = ws + off; off += (size_t)NMAX * CC;
    float* agg_a = ws + off; off += (size_t)NA * CC;
    float* agg_b = ws + off; off += (size_t)NB * CC;
    int* iw = (int*)(ws + off);
    size_t ioff = 0;
    int* cnt_b   = iw + ioff; ioff += NB;
    int* rowp_b  = iw + ioff; ioff += NB + 1;
    int* off_b   = iw + ioff; ioff += NB;
    int* srcs_ab = iw + ioff; ioff += Eab;
    int* cnt_a   = iw + ioff; ioff += NA;
    int* rowp_a  = iw + ioff; ioff += NA + 1;
    int* off_a   = iw + ioff; ioff += NA;
    int* srcs_ba = iw + ioff; ioff += Eba;

    k_init<<<dim3((NA * CC / 4 + 255) / 256), dim3(256), 0, stream>>>(
        (const float4*)x_a_in, (float4*)xa, NA * CC / 4);
    k_init<<<dim3((NB * CC / 4 + 255) / 256), dim3(256), 0, stream>>>(
        (const float4*)x_b_in, (float4*)xb, NB * CC / 4);

    // CSR for a->b (dst = b)
    hipMemsetAsync(cnt_b, 0, (size_t)NB * sizeof(int), stream);
    k_hist<<<dim3((Eab + 255) / 256), dim3(256), 0, stream>>>(e_ab + Eab, Eab, cnt_b);
    k_scan<<<dim3(1), dim3(SCAN_T), 0, stream>>>(cnt_b, rowp_b, off_b, NB);
    k_scatter<<<dim3((Eab + 255) / 256), dim3(256), 0, stream>>>(
        e_ab, e_ab + Eab, Eab, off_b, srcs_ab);

    // CSR for b->a (dst = a)
    hipMemsetAsync(cnt_a, 0, (size_t)NA * sizeof(int), stream);
    k_hist<<<dim3((Eba + 255) / 256), dim3(256), 0, stream>>>(e_ba + Eba, Eba, cnt_a);
    k_scan<<<dim3(1), dim3(SCAN_T), 0, stream>>>(cnt_a, rowp_a, off_a, NA);
    k_scatter<<<dim3((Eba + 255) / 256), dim3(256), 0, stream>>>(
        e_ba, e_ba + Eba, Eba, off_a, srcs_ba);

    for (int l = 0; l < 2; ++l) {
        int t0 = l * 2 + 0;   // conv a->b (dst = b)
        int t1 = l * 2 + 1;   // conv b->a (dst = a)

        k_pred<<<dim3((NB + TN - 1) / TN), dim3(256), 0, stream>>>(
            xb, prd, NB, pw1 + (size_t)t0 * CC * CC, pb1 + t0 * CC,
            pw2 + (size_t)t0 * CC * CC, pb2 + t0 * CC);
        k_agg<<<dim3((NB + 3) / 4), dim3(256), 0, stream>>>(
            rowp_b, srcs_ab, xa, prd, mgam + t0 * CC, mbet + t0 * CC, agg_b, NB);

        k_pred<<<dim3((NA + TN - 1) / TN), dim3(256), 0, stream>>>(
            xa, prd, NA, pw1 + (size_t)t1 * CC * CC, pb1 + t1 * CC,
            pw2 + (size_t)t1 * CC * CC, pb2 + t1 * CC);
        k_agg<<<dim3((NA + 3) / 4), dim3(256), 0, stream>>>(
            rowp_a, srcs_ba, xb, prd, mgam + t1 * CC, mbet + t1 * CC, agg_a, NA);

        // in-place updates: both convs above already consumed xa/xb
        k_update<<<dim3((NB + TN - 1) / TN), dim3(256), 0, stream>>>(
            xb, agg_b, xb, NB,
            uw + (size_t)t0 * 2 * CC * CC, ubias + t0 * CC,
            ngam + t0 * CC, nbet + t0 * CC);
        k_update<<<dim3((NA + TN - 1) / TN), dim3(256), 0, stream>>>(
            xa, agg_a, xa, NA,
            uw + (size_t)t1 * 2 * CC * CC, ubias + t1 * CC,
            ngam + t1 * CC, nbet + t1 * CC);
    }

    k_head<<<dim3((out_size + 3) / 4), dim3(256), 0, stream>>>(
        xa, hw, hb, (float*)d_out, out_size);
}

// Round 3
// 350.931 us; speedup vs baseline: 1.8882x; 1.6025x over previous
//
#include <hip/hip_runtime.h>

#define CC 128
#define SCAN_T 1024
#define SCAN_I 4

typedef __attribute__((ext_vector_type(8))) short bf16x8;
typedef __attribute__((ext_vector_type(4))) float f32x4;
#define MFMA16(a, b, c) __builtin_amdgcn_mfma_f32_16x16x32_bf16(a, b, c, 0, 0, 0)

__device__ __forceinline__ float enc_nan(float v) {
    if (v != v) return 0.f;
    if (v > 3.0e38f) return 1.f;
    if (v < -3.0e38f) return -1.f;
    return v;
}

__device__ __forceinline__ ushort f2bf(float x) {
    unsigned u = __builtin_bit_cast(unsigned, x);
    u += 0x7fff + ((u >> 16) & 1);
    return (ushort)(u >> 16);
}

// swizzled LDS index (ushort units): XOR k-bits 3..5 with row&7 -> 16B-slot spread
__device__ __forceinline__ int swz128(int row, int k) { return (row * 128 + k) ^ ((row & 7) << 3); }
__device__ __forceinline__ int swz256(int row, int k) { return (row * 256 + k) ^ ((row & 7) << 3); }

__global__ __launch_bounds__(256)
void k_init(const float4* __restrict__ xin, float4* __restrict__ xout, int n4) {
    int i = blockIdx.x * 256 + threadIdx.x;
    if (i < n4) {
        float4 v = xin[i];
        v.x = enc_nan(v.x); v.y = enc_nan(v.y); v.z = enc_nan(v.z); v.w = enc_nan(v.w);
        xout[i] = v;
    }
}

// ---------- weight convert + transpose to bf16 [col][k] ----------
__global__ __launch_bounds__(256)
void k_wcvt(const float* __restrict__ pw1, const float* __restrict__ pw2,
            const float* __restrict__ uw,
            ushort* __restrict__ w1t, ushort* __restrict__ w2t, ushort* __restrict__ uwt)
{
    int i = blockIdx.x * 256 + threadIdx.x;   // 4 types x 65536
    int t = i >> 16;
    int r = i & 65535;
    if (r < 16384) {
        int k = r >> 7, c = r & 127;
        w1t[(size_t)t * 16384 + c * 128 + k] = f2bf(pw1[(size_t)t * 16384 + k * 128 + c]);
    } else if (r < 32768) {
        int rr = r - 16384;
        int k = rr >> 7, c = rr & 127;
        w2t[(size_t)t * 16384 + c * 128 + k] = f2bf(pw2[(size_t)t * 16384 + k * 128 + c]);
    } else {
        int rr = r - 32768;                    // [0, 32768)
        int k = rr >> 7, c = rr & 127;         // k in [0,256)
        uwt[(size_t)t * 32768 + c * 256 + k] = f2bf(uw[(size_t)t * 32768 + k * 128 + c]);
    }
}

// ---------- CSR build ----------
__global__ __launch_bounds__(256)
void k_hist(const int* __restrict__ dst, int n, int* __restrict__ cnt) {
    int i = blockIdx.x * 256 + threadIdx.x;
    if (i < n) atomicAdd(&cnt[dst[i]], 1);
}

__global__ __launch_bounds__(SCAN_T)
void k_scan(const int* __restrict__ cnt, int* __restrict__ row_ptr,
            int* __restrict__ off, int n)
{
    __shared__ int wsum[SCAN_T / 64];
    __shared__ int carry_s;
    const int tid = threadIdx.x, lane = tid & 63, wid = tid >> 6;
    if (tid == 0) carry_s = 0;
    __syncthreads();
    const int chunk = SCAN_T * SCAN_I;
    for (int base = 0; base < n; base += chunk) {
        int i0 = base + tid * SCAN_I;
        int v[SCAN_I];
        int local = 0;
        #pragma unroll
        for (int t = 0; t < SCAN_I; ++t) {
            int i = i0 + t;
            v[t] = (i < n) ? cnt[i] : 0;
            local += v[t];
        }
        int incl = local;
        #pragma unroll
        for (int d = 1; d < 64; d <<= 1) {
            int t = __shfl_up(incl, d);
            if (lane >= d) incl += t;
        }
        if (lane == 63) wsum[wid] = incl;
        __syncthreads();
        if (wid == 0) {
            int wv = (lane < SCAN_T / 64) ? wsum[lane] : 0;
            int winc = wv;
            #pragma unroll
            for (int d = 1; d < SCAN_T / 64; d <<= 1) {
                int t = __shfl_up(winc, d);
                if (lane >= d) winc += t;
            }
            if (lane < SCAN_T / 64) wsum[lane] = winc - wv;
        }
        __syncthreads();
        int carry = carry_s;
        int excl = carry + wsum[wid] + incl - local;
        #pragma unroll
        for (int t = 0; t < SCAN_I; ++t) {
            int i = i0 + t;
            if (i < n) { row_ptr[i] = excl; off[i] = excl; }
            excl += v[t];
        }
        __syncthreads();
        if (tid == SCAN_T - 1) carry_s = carry + wsum[SCAN_T / 64 - 1] + incl;
        __syncthreads();
    }
    if (threadIdx.x == 0) row_ptr[n] = carry_s;
}

__global__ __launch_bounds__(256)
void k_scatter(const int* __restrict__ src, const int* __restrict__ dst, int n,
               int* __restrict__ off, int* __restrict__ srcs)
{
    int i = blockIdx.x * 256 + threadIdx.x;
    if (i < n) {
        int p = atomicAdd(&off[dst[i]], 1);
        srcs[p] = src[i];
    }
}

// ---------- pred = relu(x @ w1 + b1) @ w2 + b2  (bf16 MFMA, 32 nodes/block) ----------
__global__ __launch_bounds__(256)
void k_pred(const float* __restrict__ x, float* __restrict__ pred, int N,
            const ushort* __restrict__ w1t, const float* __restrict__ b1,
            const ushort* __restrict__ w2t, const float* __restrict__ b2)
{
    __shared__ __align__(16) ushort As[32 * 128];
    __shared__ __align__(16) ushort Hs[32 * 128];
    const int tid = threadIdx.x;
    const int base = blockIdx.x * 32;

    {   // stage x -> As (bf16, swizzled): thread = (row, 16-chunk)
        int row = tid >> 3, k0 = (tid & 7) << 4;
        int node = base + row;
        ushort h[16];
        if (node < N) {
            #pragma unroll
            for (int q = 0; q < 4; ++q) {
                float4 f = *reinterpret_cast<const float4*>(x + (size_t)node * CC + k0 + q * 4);
                h[q * 4 + 0] = f2bf(f.x); h[q * 4 + 1] = f2bf(f.y);
                h[q * 4 + 2] = f2bf(f.z); h[q * 4 + 3] = f2bf(f.w);
            }
        } else {
            #pragma unroll
            for (int q = 0; q < 16; ++q) h[q] = 0;
        }
        *reinterpret_cast<bf16x8*>(&As[swz128(row, k0)])     = *reinterpret_cast<bf16x8*>(&h[0]);
        *reinterpret_cast<bf16x8*>(&As[swz128(row, k0 + 8)]) = *reinterpret_cast<bf16x8*>(&h[8]);
    }
    __syncthreads();

    const int w = tid >> 6, l = tid & 63;
    const int lr = l & 15, lg = l >> 4;

    f32x4 acc[2][2] = {};
    for (int kb = 0; kb < 4; ++kb) {
        int k = kb * 32 + lg * 8;
        bf16x8 a0 = *reinterpret_cast<const bf16x8*>(&As[swz128(lr, k)]);
        bf16x8 a1 = *reinterpret_cast<const bf16x8*>(&As[swz128(lr + 16, k)]);
        bf16x8 b0 = *reinterpret_cast<const bf16x8*>(&w1t[(size_t)(w * 32 + lr) * 128 + k]);
        bf16x8 b1v = *reinterpret_cast<const bf16x8*>(&w1t[(size_t)(w * 32 + 16 + lr) * 128 + k]);
        acc[0][0] = MFMA16(a0, b0, acc[0][0]);
        acc[0][1] = MFMA16(a0, b1v, acc[0][1]);
        acc[1][0] = MFMA16(a1, b0, acc[1][0]);
        acc[1][1] = MFMA16(a1, b1v, acc[1][1]);
    }
    {
        float bc[2] = { b1[w * 32 + lr], b1[w * 32 + 16 + lr] };
        #pragma unroll
        for (int mi = 0; mi < 2; ++mi)
            #pragma unroll
            for (int ni = 0; ni < 2; ++ni) {
                int col = w * 32 + ni * 16 + lr;
                #pragma unroll
                for (int j = 0; j < 4; ++j) {
                    int row = mi * 16 + lg * 4 + j;
                    Hs[swz128(row, col)] = f2bf(fmaxf(acc[mi][ni][j] + bc[ni], 0.f));
                }
            }
    }
    __syncthreads();

    f32x4 acc2[2][2] = {};
    for (int kb = 0; kb < 4; ++kb) {
        int k = kb * 32 + lg * 8;
        bf16x8 a0 = *reinterpret_cast<const bf16x8*>(&Hs[swz128(lr, k)]);
        bf16x8 a1 = *reinterpret_cast<const bf16x8*>(&Hs[swz128(lr + 16, k)]);
        bf16x8 b0 = *reinterpret_cast<const bf16x8*>(&w2t[(size_t)(w * 32 + lr) * 128 + k]);
        bf16x8 b1v = *reinterpret_cast<const bf16x8*>(&w2t[(size_t)(w * 32 + 16 + lr) * 128 + k]);
        acc2[0][0] = MFMA16(a0, b0, acc2[0][0]);
        acc2[0][1] = MFMA16(a0, b1v, acc2[0][1]);
        acc2[1][0] = MFMA16(a1, b0, acc2[1][0]);
        acc2[1][1] = MFMA16(a1, b1v, acc2[1][1]);
    }
    {
        float bc[2] = { b2[w * 32 + lr], b2[w * 32 + 16 + lr] };
        #pragma unroll
        for (int mi = 0; mi < 2; ++mi)
            #pragma unroll
            for (int ni = 0; ni < 2; ++ni) {
                int col = w * 32 + ni * 16 + lr;
                #pragma unroll
                for (int j = 0; j < 4; ++j) {
                    int row = mi * 16 + lg * 4 + j;
                    int node = base + row;
                    if (node < N)
                        pred[(size_t)node * CC + col] = acc2[mi][ni][j] + bc[ni];
                }
            }
    }
}

// ---------- gather-side aggregation (2-edge ILP unroll) ----------
__global__ __launch_bounds__(256)
void k_agg(const int* __restrict__ row_ptr, const int* __restrict__ srcs,
           const float* __restrict__ xsrc, const float* __restrict__ pred,
           const float* __restrict__ g, const float* __restrict__ be,
           float* __restrict__ agg, int N)
{
    int d = blockIdx.x * 4 + (threadIdx.x >> 6);
    int lane = threadIdx.x & 63;
    if (d >= N) return;
    int jb = row_ptr[d], je = row_ptr[d + 1];
    int deg = je - jb;
    const int c = lane * 2;
    float2 pr = *reinterpret_cast<const float2*>(pred + (size_t)d * CC + c);
    float g0 = g[c], g1 = g[c + 1], b0 = be[c], b1 = be[c + 1];
    float a0 = 0.f, a1 = 0.f;
    int j = jb;
    for (; j + 2 <= je; j += 2) {
        float2 xA = *reinterpret_cast<const float2*>(xsrc + (size_t)srcs[j] * CC + c);
        float2 xB = *reinterpret_cast<const float2*>(xsrc + (size_t)srcs[j + 1] * CC + c);
        float dA0 = xA.x - pr.x, dA1 = xA.y - pr.y;
        float dB0 = xB.x - pr.x, dB1 = xB.y - pr.y;
        float sA = dA0 + dA1, qA = fmaf(dA0, dA0, dA1 * dA1);
        float sB = dB0 + dB1, qB = fmaf(dB0, dB0, dB1 * dB1);
        #pragma unroll
        for (int m = 1; m < 64; m <<= 1) {
            sA += __shfl_xor(sA, m); qA += __shfl_xor(qA, m);
            sB += __shfl_xor(sB, m); qB += __shfl_xor(qB, m);
        }
        float mA = sA * (1.f / 128.f), mB = sB * (1.f / 128.f);
        float rA = rsqrtf(qA * (1.f / 128.f) - mA * mA + 1e-5f);
        float rB = rsqrtf(qB * (1.f / 128.f) - mB * mB + 1e-5f);
        a0 += fmaf((dA0 - mA) * rA, g0, b0) + fmaf((dB0 - mB) * rB, g0, b0);
        a1 += fmaf((dA1 - mA) * rA, g1, b1) + fmaf((dB1 - mB) * rB, g1, b1);
    }
    if (j < je) {
        float2 xA = *reinterpret_cast<const float2*>(xsrc + (size_t)srcs[j] * CC + c);
        float dA0 = xA.x - pr.x, dA1 = xA.y - pr.y;
        float sA = dA0 + dA1, qA = fmaf(dA0, dA0, dA1 * dA1);
        #pragma unroll
        for (int m = 1; m < 64; m <<= 1) { sA += __shfl_xor(sA, m); qA += __shfl_xor(qA, m); }
        float mA = sA * (1.f / 128.f);
        float rA = rsqrtf(qA * (1.f / 128.f) - mA * mA + 1e-5f);
        a0 += fmaf((dA0 - mA) * rA, g0, b0);
        a1 += fmaf((dA1 - mA) * rA, g1, b1);
    }
    if (deg > 0) {
        float inv = 1.f / (float)deg;
        a0 *= inv; a1 *= inv;
    }
    *reinterpret_cast<float2*>(agg + (size_t)d * CC + c) = make_float2(a0, a1);
}

// ---------- x = relu(LN(relu(concat(x, agg) @ uw + ub)))  bf16 MFMA ----------
__global__ __launch_bounds__(256)
void k_update(const float* __restrict__ xdst, const float* __restrict__ agg,
              float* __restrict__ xnext, int N,
              const ushort* __restrict__ uwt, const float* __restrict__ ub,
              const float* __restrict__ ng, const float* __restrict__ nb)
{
    __shared__ __align__(16) ushort As[32 * 256];
    __shared__ float os[32][CC + 4];
    const int tid = threadIdx.x;
    const int base = blockIdx.x * 32;

    {   // stage concat(x, agg) -> As (bf16, swizzled)
        int row = tid >> 3, k0 = (tid & 7) << 4;
        int node = base + row;
        ushort h[16], h2[16];
        if (node < N) {
            #pragma unroll
            for (int q = 0; q < 4; ++q) {
                float4 f = *reinterpret_cast<const float4*>(xdst + (size_t)node * CC + k0 + q * 4);
                h[q * 4 + 0] = f2bf(f.x); h[q * 4 + 1] = f2bf(f.y);
                h[q * 4 + 2] = f2bf(f.z); h[q * 4 + 3] = f2bf(f.w);
            }
            #pragma unroll
            for (int q = 0; q < 4; ++q) {
                float4 f = *reinterpret_cast<const float4*>(agg + (size_t)node * CC + k0 + q * 4);
                h2[q * 4 + 0] = f2bf(f.x); h2[q * 4 + 1] = f2bf(f.y);
                h2[q * 4 + 2] = f2bf(f.z); h2[q * 4 + 3] = f2bf(f.w);
            }
        } else {
            #pragma unroll
            for (int q = 0; q < 16; ++q) { h[q] = 0; h2[q] = 0; }
        }
        *reinterpret_cast<bf16x8*>(&As[swz256(row, k0)])           = *reinterpret_cast<bf16x8*>(&h[0]);
        *reinterpret_cast<bf16x8*>(&As[swz256(row, k0 + 8)])       = *reinterpret_cast<bf16x8*>(&h[8]);
        *reinterpret_cast<bf16x8*>(&As[swz256(row, 128 + k0)])     = *reinterpret_cast<bf16x8*>(&h2[0]);
        *reinterpret_cast<bf16x8*>(&As[swz256(row, 128 + k0 + 8)]) = *reinterpret_cast<bf16x8*>(&h2[8]);
    }
    __syncthreads();

    const int w = tid >> 6, l = tid & 63;
    const int lr = l & 15, lg = l >> 4;

    f32x4 acc[2][2] = {};
    for (int kb = 0; kb < 8; ++kb) {
        int k = kb * 32 + lg * 8;
        bf16x8 a0 = *reinterpret_cast<const bf16x8*>(&As[swz256(lr, k)]);
        bf16x8 a1 = *reinterpret_cast<const bf16x8*>(&As[swz256(lr + 16, k)]);
        bf16x8 b0 = *reinterpret_cast<const bf16x8*>(&uwt[(size_t)(w * 32 + lr) * 256 + k]);
        bf16x8 b1v = *reinterpret_cast<const bf16x8*>(&uwt[(size_t)(w * 32 + 16 + lr) * 256 + k]);
        acc[0][0] = MFMA16(a0, b0, acc[0][0]);
        acc[0][1] = MFMA16(a0, b1v, acc[0][1]);
        acc[1][0] = MFMA16(a1, b0, acc[1][0]);
        acc[1][1] = MFMA16(a1, b1v, acc[1][1]);
    }
    {
        float bc[2] = { ub[w * 32 + lr], ub[w * 32 + 16 + lr] };
        #pragma unroll
        for (int mi = 0; mi < 2; ++mi)
            #pragma unroll
            for (int ni = 0; ni < 2; ++ni) {
                int col = w * 32 + ni * 16 + lr;
                #pragma unroll
                for (int j = 0; j < 4; ++j) {
                    int row = mi * 16 + lg * 4 + j;
                    os[row][col] = fmaxf(acc[mi][ni][j] + bc[ni], 0.f);
                }
            }
    }
    __syncthreads();

    // node LayerNorm + relu; 8 lanes per node, 16 channels per lane
    const int wv_ = tid >> 6;
    const int lane = tid & 63;
    const int nl = wv_ * 8 + (lane >> 3);
    const int cl = lane & 7;
    float vals[16];
    float sm = 0.f, sq = 0.f;
    #pragma unroll
    for (int t = 0; t < 16; ++t) {
        float u = os[nl][cl + 8 * t];
        vals[t] = u; sm += u; sq = fmaf(u, u, sq);
    }
    #pragma unroll
    for (int m = 1; m < 8; m <<= 1) { sm += __shfl_xor(sm, m); sq += __shfl_xor(sq, m); }
    float mean = sm * (1.f / 128.f);
    float var = sq * (1.f / 128.f) - mean * mean;
    float r = rsqrtf(var + 1e-5f);
    int node = base + nl;
    if (node < N) {
        #pragma unroll
        for (int t = 0; t < 16; ++t) {
            int cch = cl + 8 * t;
            float o = fmaxf(fmaf((vals[t] - mean) * r, ng[cch], nb[cch]), 0.f);
            xnext[(size_t)node * CC + cch] = o;
        }
    }
}

__global__ __launch_bounds__(256)
void k_head(const float* __restrict__ xa, const float* __restrict__ hw,
            const float* __restrict__ hb, float* __restrict__ out, int S)
{
    int w = blockIdx.x * 4 + (threadIdx.x >> 6);
    int lane = threadIdx.x & 63;
    if (w >= S) return;
    float v = fmaf(xa[(size_t)w * CC + lane], hw[lane],
                   xa[(size_t)w * CC + lane + 64] * hw[lane + 64]);
    #pragma unroll
    for (int m = 1; m < 64; m <<= 1) v += __shfl_xor(v, m);
    if (lane == 0) out[w] = v + hb[0];
}

extern "C" void kernel_launch(void* const* d_in, const int* in_sizes, int n_in,
                              void* d_out, int out_size, void* d_ws, size_t ws_size,
                              hipStream_t stream)
{
    const float* x_a_in = (const float*)d_in[0];
    const float* x_b_in = (const float*)d_in[1];
    const int*   e_ab   = (const int*)d_in[2];
    const int*   e_ba   = (const int*)d_in[3];
    const float* pw1    = (const float*)d_in[4];
    const float* pb1    = (const float*)d_in[5];
    const float* pw2    = (const float*)d_in[6];
    const float* pb2    = (const float*)d_in[7];
    const float* mgam   = (const float*)d_in[8];
    const float* mbet   = (const float*)d_in[9];
    const float* uw     = (const float*)d_in[10];
    const float* ubias  = (const float*)d_in[11];
    const float* ngam   = (const float*)d_in[12];
    const float* nbet   = (const float*)d_in[13];
    const float* hw     = (const float*)d_in[14];
    const float* hb     = (const float*)d_in[15];

    const int NA  = in_sizes[0] / CC;
    const int NB  = in_sizes[1] / CC;
    const int Eab = in_sizes[2] / 2;
    const int Eba = in_sizes[3] / 2;
    const int NMAX = NA > NB ? NA : NB;

    float* ws = (float*)d_ws;
    size_t off = 0;
    float* xa    = ws + off; off += (size_t)NA * CC;
    float* xb    = ws + off; off += (size_t)NB * CC;
    float* prd   = ws + off; off += (size_t)NMAX * CC;
    float* agg_a = ws + off; off += (size_t)NA * CC;
    float* agg_b = ws + off; off += (size_t)NB * CC;
    ushort* w1t  = (ushort*)(ws + off); off += 4 * 16384 / 2;
    ushort* w2t  = (ushort*)(ws + off); off += 4 * 16384 / 2;
    ushort* uwt  = (ushort*)(ws + off); off += 4 * 32768 / 2;
    int* iw = (int*)(ws + off);
    size_t ioff = 0;
    int* cnt_b   = iw + ioff; ioff += NB;
    int* rowp_b  = iw + ioff; ioff += NB + 1;
    int* off_b   = iw + ioff; ioff += NB;
    int* srcs_ab = iw + ioff; ioff += Eab;
    int* cnt_a   = iw + ioff; ioff += NA;
    int* rowp_a  = iw + ioff; ioff += NA + 1;
    int* off_a   = iw + ioff; ioff += NA;
    int* srcs_ba = iw + ioff; ioff += Eba;

    k_init<<<dim3((NA * CC / 4 + 255) / 256), dim3(256), 0, stream>>>(
        (const float4*)x_a_in, (float4*)xa, NA * CC / 4);
    k_init<<<dim3((NB * CC / 4 + 255) / 256), dim3(256), 0, stream>>>(
        (const float4*)x_b_in, (float4*)xb, NB * CC / 4);

    k_wcvt<<<dim3(1024), dim3(256), 0, stream>>>(pw1, pw2, uw, w1t, w2t, uwt);

    // CSR for a->b (dst = b)
    hipMemsetAsync(cnt_b, 0, (size_t)NB * sizeof(int), stream);
    k_hist<<<dim3((Eab + 255) / 256), dim3(256), 0, stream>>>(e_ab + Eab, Eab, cnt_b);
    k_scan<<<dim3(1), dim3(SCAN_T), 0, stream>>>(cnt_b, rowp_b, off_b, NB);
    k_scatter<<<dim3((Eab + 255) / 256), dim3(256), 0, stream>>>(
        e_ab, e_ab + Eab, Eab, off_b, srcs_ab);

    // CSR for b->a (dst = a)
    hipMemsetAsync(cnt_a, 0, (size_t)NA * sizeof(int), stream);
    k_hist<<<dim3((Eba + 255) / 256), dim3(256), 0, stream>>>(e_ba + Eba, Eba, cnt_a);
    k_scan<<<dim3(1), dim3(SCAN_T), 0, stream>>>(cnt_a, rowp_a, off_a, NA);
    k_scatter<<<dim3((Eba + 255) / 256), dim3(256), 0, stream>>>(
        e_ba, e_ba + Eba, Eba, off_a, srcs_ba);

    for (int l = 0; l < 2; ++l) {
        int t0 = l * 2 + 0;   // conv a->b (dst = b)
        int t1 = l * 2 + 1;   // conv b->a (dst = a)

        k_pred<<<dim3((NB + 31) / 32), dim3(256), 0, stream>>>(
            xb, prd, NB, w1t + (size_t)t0 * 16384, pb1 + t0 * CC,
            w2t + (size_t)t0 * 16384, pb2 + t0 * CC);
        k_agg<<<dim3((NB + 3) / 4), dim3(256), 0, stream>>>(
            rowp_b, srcs_ab, xa, prd, mgam + t0 * CC, mbet + t0 * CC, agg_b, NB);

        k_pred<<<dim3((NA + 31) / 32), dim3(256), 0, stream>>>(
            xa, prd, NA, w1t + (size_t)t1 * 16384, pb1 + t1 * CC,
            w2t + (size_t)t1 * 16384, pb2 + t1 * CC);
        k_agg<<<dim3((NA + 3) / 4), dim3(256), 0, stream>>>(
            rowp_a, srcs_ba, xb, prd, mgam + t1 * CC, mbet + t1 * CC, agg_a, NA);

        k_update<<<dim3((NB + 31) / 32), dim3(256), 0, stream>>>(
            xb, agg_b, xb, NB, uwt + (size_t)t0 * 32768, ubias + t0 * CC,
            ngam + t0 * CC, nbet + t0 * CC);
        k_update<<<dim3((NA + 31) / 32), dim3(256), 0, stream>>>(
            xa, agg_a, xa, NA, uwt + (size_t)t1 * 32768, ubias + t1 * CC,
            ngam + t1 * CC, nbet + t1 * CC);
    }

    k_head<<<dim3((out_size + 3) / 4), dim3(256), 0, stream>>>(
        xa, hw, hb, (float*)d_out, out_size);
}

// Round 4
// 274.845 us; speedup vs baseline: 2.4109x; 1.2768x over previous
//
#include <hip/hip_runtime.h>

#define CC 128
#define SCAN_T 1024
#define SCAN_I 4

typedef __attribute__((ext_vector_type(8))) short bf16x8;
typedef __attribute__((ext_vector_type(4))) float f32x4;
#define MFMA16(a, b, c) __builtin_amdgcn_mfma_f32_16x16x32_bf16(a, b, c, 0, 0, 0)

__device__ __forceinline__ float enc_nan(float v) {
    if (v != v) return 0.f;
    if (v > 3.0e38f) return 1.f;
    if (v < -3.0e38f) return -1.f;
    return v;
}

__device__ __forceinline__ ushort f2bf(float x) {
    unsigned u = __builtin_bit_cast(unsigned, x);
    u += 0x7fff + ((u >> 16) & 1);
    return (ushort)(u >> 16);
}

__device__ __forceinline__ int swz128(int row, int k) { return (row * 128 + k) ^ ((row & 7) << 3); }
__device__ __forceinline__ int swz256(int row, int k) { return (row * 256 + k) ^ ((row & 7) << 3); }

// ---------- init: nan_to_num copy + per-row (sum, sumsq) stats ----------
__global__ __launch_bounds__(256)
void k_init(const float* __restrict__ xin, float* __restrict__ xout,
            float2* __restrict__ stat, int N)
{
    int row = blockIdx.x * 8 + (threadIdx.x >> 5);
    int s = threadIdx.x & 31;
    if (row >= N) return;
    float4 v = *reinterpret_cast<const float4*>(xin + (size_t)row * CC + s * 4);
    v.x = enc_nan(v.x); v.y = enc_nan(v.y); v.z = enc_nan(v.z); v.w = enc_nan(v.w);
    *reinterpret_cast<float4*>(xout + (size_t)row * CC + s * 4) = v;
    float sm = (v.x + v.y) + (v.z + v.w);
    float sq = fmaf(v.x, v.x, fmaf(v.y, v.y, fmaf(v.z, v.z, v.w * v.w)));
    #pragma unroll
    for (int m = 1; m < 32; m <<= 1) { sm += __shfl_xor(sm, m); sq += __shfl_xor(sq, m); }
    if (s == 0) stat[row] = make_float2(sm, sq);
}

// ---------- weight convert + transpose to bf16 [col][k] ----------
__global__ __launch_bounds__(256)
void k_wcvt(const float* __restrict__ pw1, const float* __restrict__ pw2,
            const float* __restrict__ uw,
            ushort* __restrict__ w1t, ushort* __restrict__ w2t, ushort* __restrict__ uwt)
{
    int i = blockIdx.x * 256 + threadIdx.x;   // 4 types x 65536
    int t = i >> 16;
    int r = i & 65535;
    if (r < 16384) {
        int k = r >> 7, c = r & 127;
        w1t[(size_t)t * 16384 + c * 128 + k] = f2bf(pw1[(size_t)t * 16384 + k * 128 + c]);
    } else if (r < 32768) {
        int rr = r - 16384;
        int k = rr >> 7, c = rr & 127;
        w2t[(size_t)t * 16384 + c * 128 + k] = f2bf(pw2[(size_t)t * 16384 + k * 128 + c]);
    } else {
        int rr = r - 32768;
        int k = rr >> 7, c = rr & 127;
        uwt[(size_t)t * 32768 + c * 256 + k] = f2bf(uw[(size_t)t * 32768 + k * 128 + c]);
    }
}

// ---------- CSR build (dual) ----------
__global__ __launch_bounds__(256)
void k_hist_dual(const int* __restrict__ dst_b, int Eab, int* __restrict__ cnt_b,
                 const int* __restrict__ dst_a, int Eba, int* __restrict__ cnt_a)
{
    int i = blockIdx.x * 256 + threadIdx.x;
    if (i < Eab) atomicAdd(&cnt_b[dst_b[i]], 1);
    else if (i - Eab < Eba) atomicAdd(&cnt_a[dst_a[i - Eab]], 1);
}

__global__ __launch_bounds__(SCAN_T)
void k_scan_dual(const int* __restrict__ cnt0, int* __restrict__ rowp0, int* __restrict__ off0, int n0,
                 const int* __restrict__ cnt1, int* __restrict__ rowp1, int* __restrict__ off1, int n1)
{
    const int* cnt = (blockIdx.x == 0) ? cnt0 : cnt1;
    int* row_ptr   = (blockIdx.x == 0) ? rowp0 : rowp1;
    int* off       = (blockIdx.x == 0) ? off0 : off1;
    int n          = (blockIdx.x == 0) ? n0 : n1;

    __shared__ int wsum[SCAN_T / 64];
    __shared__ int carry_s;
    const int tid = threadIdx.x, lane = tid & 63, wid = tid >> 6;
    if (tid == 0) carry_s = 0;
    __syncthreads();
    const int chunk = SCAN_T * SCAN_I;
    for (int base = 0; base < n; base += chunk) {
        int i0 = base + tid * SCAN_I;
        int v[SCAN_I];
        int local = 0;
        #pragma unroll
        for (int t = 0; t < SCAN_I; ++t) {
            int i = i0 + t;
            v[t] = (i < n) ? cnt[i] : 0;
            local += v[t];
        }
        int incl = local;
        #pragma unroll
        for (int d = 1; d < 64; d <<= 1) {
            int t = __shfl_up(incl, d);
            if (lane >= d) incl += t;
        }
        if (lane == 63) wsum[wid] = incl;
        __syncthreads();
        if (wid == 0) {
            int wv = (lane < SCAN_T / 64) ? wsum[lane] : 0;
            int winc = wv;
            #pragma unroll
            for (int d = 1; d < SCAN_T / 64; d <<= 1) {
                int t = __shfl_up(winc, d);
                if (lane >= d) winc += t;
            }
            if (lane < SCAN_T / 64) wsum[lane] = winc - wv;
        }
        __syncthreads();
        int carry = carry_s;
        int excl = carry + wsum[wid] + incl - local;
        #pragma unroll
        for (int t = 0; t < SCAN_I; ++t) {
            int i = i0 + t;
            if (i < n) { row_ptr[i] = excl; off[i] = excl; }
            excl += v[t];
        }
        __syncthreads();
        if (tid == SCAN_T - 1) carry_s = carry + wsum[SCAN_T / 64 - 1] + incl;
        __syncthreads();
    }
    if (threadIdx.x == 0) row_ptr[n] = carry_s;
}

__global__ __launch_bounds__(256)
void k_scatter_dual(const int* __restrict__ src_b, const int* __restrict__ dst_b, int Eab,
                    int* __restrict__ off_b, int* __restrict__ srcs_ab,
                    const int* __restrict__ src_a, const int* __restrict__ dst_a, int Eba,
                    int* __restrict__ off_a, int* __restrict__ srcs_ba)
{
    int i = blockIdx.x * 256 + threadIdx.x;
    if (i < Eab) {
        int p = atomicAdd(&off_b[dst_b[i]], 1);
        srcs_ab[p] = src_b[i];
    } else if (i - Eab < Eba) {
        int j = i - Eab;
        int p = atomicAdd(&off_a[dst_a[j]], 1);
        srcs_ba[p] = src_a[j];
    }
}

// ---------- pred = relu(x @ w1 + b1) @ w2 + b2  (bf16 MFMA, 32 nodes/block) ----------
__device__ __forceinline__ void pred_body(
    ushort* As, ushort* Hs,
    const float* __restrict__ x, float* __restrict__ pred, int N, int blk,
    const ushort* __restrict__ w1t, const float* __restrict__ b1,
    const ushort* __restrict__ w2t, const float* __restrict__ b2)
{
    const int tid = threadIdx.x;
    const int base = blk * 32;

    {
        int row = tid >> 3, k0 = (tid & 7) << 4;
        int node = base + row;
        ushort h[16];
        if (node < N) {
            #pragma unroll
            for (int q = 0; q < 4; ++q) {
                float4 f = *reinterpret_cast<const float4*>(x + (size_t)node * CC + k0 + q * 4);
                h[q * 4 + 0] = f2bf(f.x); h[q * 4 + 1] = f2bf(f.y);
                h[q * 4 + 2] = f2bf(f.z); h[q * 4 + 3] = f2bf(f.w);
            }
        } else {
            #pragma unroll
            for (int q = 0; q < 16; ++q) h[q] = 0;
        }
        *reinterpret_cast<bf16x8*>(&As[swz128(row, k0)])     = *reinterpret_cast<bf16x8*>(&h[0]);
        *reinterpret_cast<bf16x8*>(&As[swz128(row, k0 + 8)]) = *reinterpret_cast<bf16x8*>(&h[8]);
    }
    __syncthreads();

    const int w = tid >> 6, l = tid & 63;
    const int lr = l & 15, lg = l >> 4;

    f32x4 acc[2][2] = {};
    for (int kb = 0; kb < 4; ++kb) {
        int k = kb * 32 + lg * 8;
        bf16x8 a0 = *reinterpret_cast<const bf16x8*>(&As[swz128(lr, k)]);
        bf16x8 a1 = *reinterpret_cast<const bf16x8*>(&As[swz128(lr + 16, k)]);
        bf16x8 b0 = *reinterpret_cast<const bf16x8*>(&w1t[(size_t)(w * 32 + lr) * 128 + k]);
        bf16x8 b1v = *reinterpret_cast<const bf16x8*>(&w1t[(size_t)(w * 32 + 16 + lr) * 128 + k]);
        acc[0][0] = MFMA16(a0, b0, acc[0][0]);
        acc[0][1] = MFMA16(a0, b1v, acc[0][1]);
        acc[1][0] = MFMA16(a1, b0, acc[1][0]);
        acc[1][1] = MFMA16(a1, b1v, acc[1][1]);
    }
    {
        float bc[2] = { b1[w * 32 + lr], b1[w * 32 + 16 + lr] };
        #pragma unroll
        for (int mi = 0; mi < 2; ++mi)
            #pragma unroll
            for (int ni = 0; ni < 2; ++ni) {
                int col = w * 32 + ni * 16 + lr;
                #pragma unroll
                for (int j = 0; j < 4; ++j) {
                    int row = mi * 16 + lg * 4 + j;
                    Hs[swz128(row, col)] = f2bf(fmaxf(acc[mi][ni][j] + bc[ni], 0.f));
                }
            }
    }
    __syncthreads();

    f32x4 acc2[2][2] = {};
    for (int kb = 0; kb < 4; ++kb) {
        int k = kb * 32 + lg * 8;
        bf16x8 a0 = *reinterpret_cast<const bf16x8*>(&Hs[swz128(lr, k)]);
        bf16x8 a1 = *reinterpret_cast<const bf16x8*>(&Hs[swz128(lr + 16, k)]);
        bf16x8 b0 = *reinterpret_cast<const bf16x8*>(&w2t[(size_t)(w * 32 + lr) * 128 + k]);
        bf16x8 b1v = *reinterpret_cast<const bf16x8*>(&w2t[(size_t)(w * 32 + 16 + lr) * 128 + k]);
        acc2[0][0] = MFMA16(a0, b0, acc2[0][0]);
        acc2[0][1] = MFMA16(a0, b1v, acc2[0][1]);
        acc2[1][0] = MFMA16(a1, b0, acc2[1][0]);
        acc2[1][1] = MFMA16(a1, b1v, acc2[1][1]);
    }
    {
        float bc[2] = { b2[w * 32 + lr], b2[w * 32 + 16 + lr] };
        #pragma unroll
        for (int mi = 0; mi < 2; ++mi)
            #pragma unroll
            for (int ni = 0; ni < 2; ++ni) {
                int col = w * 32 + ni * 16 + lr;
                #pragma unroll
                for (int j = 0; j < 4; ++j) {
                    int row = mi * 16 + lg * 4 + j;
                    int node = base + row;
                    if (node < N)
                        pred[(size_t)node * CC + col] = acc2[mi][ni][j] + bc[ni];
                }
            }
    }
}

__global__ __launch_bounds__(256)
void k_pred_dual(const float* __restrict__ xb, float* __restrict__ prd_b, int NB, int GB,
                 const ushort* __restrict__ w1t0, const float* __restrict__ b10,
                 const ushort* __restrict__ w2t0, const float* __restrict__ b20,
                 const float* __restrict__ xa, float* __restrict__ prd_a, int NA,
                 const ushort* __restrict__ w1t1, const float* __restrict__ b11,
                 const ushort* __restrict__ w2t1, const float* __restrict__ b21)
{
    __shared__ __align__(16) ushort As[32 * 128];
    __shared__ __align__(16) ushort Hs[32 * 128];
    if ((int)blockIdx.x < GB)
        pred_body(As, Hs, xb, prd_b, NB, blockIdx.x, w1t0, b10, w2t0, b20);
    else
        pred_body(As, Hs, xa, prd_a, NA, blockIdx.x - GB, w1t1, b11, w2t1, b21);
}

// ---------- gather aggregation: wave = dst node, halves = edge pair ----------
__device__ __forceinline__ void agg_body(
    const int* __restrict__ rowp, const int* __restrict__ srcs,
    const float* __restrict__ xsrc, const float2* __restrict__ statx,
    const float* __restrict__ pred, const float* __restrict__ g,
    const float* __restrict__ be, float* __restrict__ agg, int N, int blk)
{
    const int wid = threadIdx.x >> 6;
    const int lane = threadIdx.x & 63;
    const int d = blk * 4 + wid;
    if (d >= N) return;
    const int half = lane >> 5;
    const int c = (lane & 31) * 4;
    const int jb = rowp[d], je = rowp[d + 1];
    const int deg = je - jb;
    const float4 pr = *reinterpret_cast<const float4*>(pred + (size_t)d * CC + c);
    // per-node pred stats (reduced within each 32-lane half; both halves identical)
    float sp = (pr.x + pr.y) + (pr.z + pr.w);
    float qp = fmaf(pr.x, pr.x, fmaf(pr.y, pr.y, fmaf(pr.z, pr.z, pr.w * pr.w)));
    #pragma unroll
    for (int m = 1; m < 32; m <<= 1) { sp += __shfl_xor(sp, m); qp += __shfl_xor(qp, m); }

    float a0 = 0.f, a1 = 0.f, a2 = 0.f, a3 = 0.f, rsum = 0.f, cmsum = 0.f;
    for (int j = jb + half; j < je; j += 2) {
        const int sidx = srcs[j];
        const float4 xj = *reinterpret_cast<const float4*>(xsrc + (size_t)sidx * CC + c);
        const float2 st = statx[sidx];
        float dot = fmaf(xj.x, pr.x, fmaf(xj.y, pr.y, fmaf(xj.z, pr.z, xj.w * pr.w)));
        #pragma unroll
        for (int m = 1; m < 32; m <<= 1) dot += __shfl_xor(dot, m);
        const float mean = (st.x - sp) * (1.f / 128.f);
        const float var = fmaf(-2.f, dot, st.y + qp) * (1.f / 128.f) - mean * mean;
        const float r = rsqrtf(var + 1e-5f);
        rsum += r;
        cmsum = fmaf(mean, r, cmsum);
        a0 = fmaf(xj.x, r, a0);
        a1 = fmaf(xj.y, r, a1);
        a2 = fmaf(xj.z, r, a2);
        a3 = fmaf(xj.w, r, a3);
    }
    a0 += __shfl_xor(a0, 32); a1 += __shfl_xor(a1, 32);
    a2 += __shfl_xor(a2, 32); a3 += __shfl_xor(a3, 32);
    rsum += __shfl_xor(rsum, 32); cmsum += __shfl_xor(cmsum, 32);
    if (half == 0) {
        float4 o = make_float4(0.f, 0.f, 0.f, 0.f);
        if (deg > 0) {
            const float inv = 1.f / (float)deg;
            const float4 gv = *reinterpret_cast<const float4*>(g + c);
            const float4 bv = *reinterpret_cast<const float4*>(be + c);
            o.x = fmaf((a0 - pr.x * rsum - cmsum) * inv, gv.x, bv.x);
            o.y = fmaf((a1 - pr.y * rsum - cmsum) * inv, gv.y, bv.y);
            o.z = fmaf((a2 - pr.z * rsum - cmsum) * inv, gv.z, bv.z);
            o.w = fmaf((a3 - pr.w * rsum - cmsum) * inv, gv.w, bv.w);
        }
        *reinterpret_cast<float4*>(agg + (size_t)d * CC + c) = o;
    }
}

__global__ __launch_bounds__(256)
void k_agg_dual(const int* __restrict__ rowp_b, const int* __restrict__ srcs_ab,
                const float* __restrict__ xa, const float2* __restrict__ stat_a,
                const float* __restrict__ prd_b, const float* __restrict__ g0,
                const float* __restrict__ be0, float* __restrict__ agg_b, int NB, int GBa,
                const int* __restrict__ rowp_a, const int* __restrict__ srcs_ba,
                const float* __restrict__ xb, const float2* __restrict__ stat_b,
                const float* __restrict__ prd_a, const float* __restrict__ g1,
                const float* __restrict__ be1, float* __restrict__ agg_a, int NA)
{
    if ((int)blockIdx.x < GBa)
        agg_body(rowp_b, srcs_ab, xa, stat_a, prd_b, g0, be0, agg_b, NB, blockIdx.x);
    else
        agg_body(rowp_a, srcs_ba, xb, stat_b, prd_a, g1, be1, agg_a, NA, blockIdx.x - GBa);
}

// ---------- x = relu(LN(relu(concat(x, agg) @ uw + ub))) + stats ----------
__device__ __forceinline__ void update_body(
    ushort* As, float (*os)[CC + 4],
    const float* __restrict__ xdst, const float* __restrict__ agg,
    float* __restrict__ xnext, float2* __restrict__ statOut, int N, int blk,
    const ushort* __restrict__ uwt, const float* __restrict__ ub,
    const float* __restrict__ ng, const float* __restrict__ nb)
{
    const int tid = threadIdx.x;
    const int base = blk * 32;

    {
        int row = tid >> 3, k0 = (tid & 7) << 4;
        int node = base + row;
        ushort h[16], h2[16];
        if (node < N) {
            #pragma unroll
            for (int q = 0; q < 4; ++q) {
                float4 f = *reinterpret_cast<const float4*>(xdst + (size_t)node * CC + k0 + q * 4);
                h[q * 4 + 0] = f2bf(f.x); h[q * 4 + 1] = f2bf(f.y);
                h[q * 4 + 2] = f2bf(f.z); h[q * 4 + 3] = f2bf(f.w);
            }
            #pragma unroll
            for (int q = 0; q < 4; ++q) {
                float4 f = *reinterpret_cast<const float4*>(agg + (size_t)node * CC + k0 + q * 4);
                h2[q * 4 + 0] = f2bf(f.x); h2[q * 4 + 1] = f2bf(f.y);
                h2[q * 4 + 2] = f2bf(f.z); h2[q * 4 + 3] = f2bf(f.w);
            }
        } else {
            #pragma unroll
            for (int q = 0; q < 16; ++q) { h[q] = 0; h2[q] = 0; }
        }
        *reinterpret_cast<bf16x8*>(&As[swz256(row, k0)])           = *reinterpret_cast<bf16x8*>(&h[0]);
        *reinterpret_cast<bf16x8*>(&As[swz256(row, k0 + 8)])       = *reinterpret_cast<bf16x8*>(&h[8]);
        *reinterpret_cast<bf16x8*>(&As[swz256(row, 128 + k0)])     = *reinterpret_cast<bf16x8*>(&h2[0]);
        *reinterpret_cast<bf16x8*>(&As[swz256(row, 128 + k0 + 8)]) = *reinterpret_cast<bf16x8*>(&h2[8]);
    }
    __syncthreads();

    const int w = tid >> 6, l = tid & 63;
    const int lr = l & 15, lg = l >> 4;

    f32x4 acc[2][2] = {};
    for (int kb = 0; kb < 8; ++kb) {
        int k = kb * 32 + lg * 8;
        bf16x8 a0 = *reinterpret_cast<const bf16x8*>(&As[swz256(lr, k)]);
        bf16x8 a1 = *reinterpret_cast<const bf16x8*>(&As[swz256(lr + 16, k)]);
        bf16x8 b0 = *reinterpret_cast<const bf16x8*>(&uwt[(size_t)(w * 32 + lr) * 256 + k]);
        bf16x8 b1v = *reinterpret_cast<const bf16x8*>(&uwt[(size_t)(w * 32 + 16 + lr) * 256 + k]);
        acc[0][0] = MFMA16(a0, b0, acc[0][0]);
        acc[0][1] = MFMA16(a0, b1v, acc[0][1]);
        acc[1][0] = MFMA16(a1, b0, acc[1][0]);
        acc[1][1] = MFMA16(a1, b1v, acc[1][1]);
    }
    {
        float bc[2] = { ub[w * 32 + lr], ub[w * 32 + 16 + lr] };
        #pragma unroll
        for (int mi = 0; mi < 2; ++mi)
            #pragma unroll
            for (int ni = 0; ni < 2; ++ni) {
                int col = w * 32 + ni * 16 + lr;
                #pragma unroll
                for (int j = 0; j < 4; ++j) {
                    int row = mi * 16 + lg * 4 + j;
                    os[row][col] = fmaxf(acc[mi][ni][j] + bc[ni], 0.f);
                }
            }
    }
    __syncthreads();

    // node LayerNorm + relu + stats; 8 lanes per node, 16 channels per lane
    const int lane = tid & 63;
    const int nl = (tid >> 6) * 8 + (lane >> 3);
    const int cl = lane & 7;
    float vals[16];
    float sm = 0.f, sq = 0.f;
    #pragma unroll
    for (int t = 0; t < 16; ++t) {
        float u = os[nl][cl + 8 * t];
        vals[t] = u; sm += u; sq = fmaf(u, u, sq);
    }
    #pragma unroll
    for (int m = 1; m < 8; m <<= 1) { sm += __shfl_xor(sm, m); sq += __shfl_xor(sq, m); }
    float mean = sm * (1.f / 128.f);
    float var = sq * (1.f / 128.f) - mean * mean;
    float r = rsqrtf(var + 1e-5f);
    int node = base + nl;
    if (node < N) {
        float so = 0.f, sqo = 0.f;
        #pragma unroll
        for (int t = 0; t < 16; ++t) {
            int cch = cl + 8 * t;
            float o = fmaxf(fmaf((vals[t] - mean) * r, ng[cch], nb[cch]), 0.f);
            xnext[(size_t)node * CC + cch] = o;
            so += o; sqo = fmaf(o, o, sqo);
        }
        #pragma unroll
        for (int m = 1; m < 8; m <<= 1) { so += __shfl_xor(so, m); sqo += __shfl_xor(sqo, m); }
        if (cl == 0) statOut[node] = make_float2(so, sqo);
    }
}

__global__ __launch_bounds__(256)
void k_update_dual(const float* __restrict__ xb, const float* __restrict__ agg_b,
                   float* __restrict__ xb_o, float2* __restrict__ stat_b, int NB, int GB,
                   const ushort* __restrict__ uwt0, const float* __restrict__ ub0,
                   const float* __restrict__ ng0, const float* __restrict__ nb0,
                   const float* __restrict__ xa, const float* __restrict__ agg_a,
                   float* __restrict__ xa_o, float2* __restrict__ stat_a, int NA,
                   const ushort* __restrict__ uwt1, const float* __restrict__ ub1,
                   const float* __restrict__ ng1, const float* __restrict__ nb1)
{
    __shared__ __align__(16) ushort As[32 * 256];
    __shared__ float os[32][CC + 4];
    if ((int)blockIdx.x < GB)
        update_body(As, os, xb, agg_b, xb_o, stat_b, NB, blockIdx.x, uwt0, ub0, ng0, nb0);
    else
        update_body(As, os, xa, agg_a, xa_o, stat_a, NA, blockIdx.x - GB, uwt1, ub1, ng1, nb1);
}

__global__ __launch_bounds__(256)
void k_head(const float* __restrict__ xa, const float* __restrict__ hw,
            const float* __restrict__ hb, float* __restrict__ out, int S)
{
    int w = blockIdx.x * 4 + (threadIdx.x >> 6);
    int lane = threadIdx.x & 63;
    if (w >= S) return;
    float v = fmaf(xa[(size_t)w * CC + lane], hw[lane],
                   xa[(size_t)w * CC + lane + 64] * hw[lane + 64]);
    #pragma unroll
    for (int m = 1; m < 64; m <<= 1) v += __shfl_xor(v, m);
    if (lane == 0) out[w] = v + hb[0];
}

extern "C" void kernel_launch(void* const* d_in, const int* in_sizes, int n_in,
                              void* d_out, int out_size, void* d_ws, size_t ws_size,
                              hipStream_t stream)
{
    const float* x_a_in = (const float*)d_in[0];
    const float* x_b_in = (const float*)d_in[1];
    const int*   e_ab   = (const int*)d_in[2];
    const int*   e_ba   = (const int*)d_in[3];
    const float* pw1    = (const float*)d_in[4];
    const float* pb1    = (const float*)d_in[5];
    const float* pw2    = (const float*)d_in[6];
    const float* pb2    = (const float*)d_in[7];
    const float* mgam   = (const float*)d_in[8];
    const float* mbet   = (const float*)d_in[9];
    const float* uw     = (const float*)d_in[10];
    const float* ubias  = (const float*)d_in[11];
    const float* ngam   = (const float*)d_in[12];
    const float* nbet   = (const float*)d_in[13];
    const float* hw     = (const float*)d_in[14];
    const float* hb     = (const float*)d_in[15];

    const int NA  = in_sizes[0] / CC;
    const int NB  = in_sizes[1] / CC;
    const int Eab = in_sizes[2] / 2;
    const int Eba = in_sizes[3] / 2;

    float* ws = (float*)d_ws;
    size_t off = 0;
    float* xa    = ws + off; off += (size_t)NA * CC;
    float* xb    = ws + off; off += (size_t)NB * CC;
    float* prd_b = ws + off; off += (size_t)NB * CC;
    float* prd_a = ws + off; off += (size_t)NA * CC;
    float* agg_a = ws + off; off += (size_t)NA * CC;
    float* agg_b = ws + off; off += (size_t)NB * CC;
    float2* stat_a = (float2*)(ws + off); off += (size_t)NA * 2;
    float2* stat_b = (float2*)(ws + off); off += (size_t)NB * 2;
    ushort* w1t  = (ushort*)(ws + off); off += 4 * 16384 / 2;
    ushort* w2t  = (ushort*)(ws + off); off += 4 * 16384 / 2;
    ushort* uwt  = (ushort*)(ws + off); off += 4 * 32768 / 2;
    int* iw = (int*)(ws + off);
    size_t ioff = 0;
    int* cnt_b   = iw + ioff; ioff += NB;
    int* cnt_a   = iw + ioff; ioff += NA;
    int* rowp_b  = iw + ioff; ioff += NB + 1;
    int* rowp_a  = iw + ioff; ioff += NA + 1;
    int* off_b   = iw + ioff; ioff += NB;
    int* off_a   = iw + ioff; ioff += NA;
    int* srcs_ab = iw + ioff; ioff += Eab;
    int* srcs_ba = iw + ioff; ioff += Eba;

    const int GB  = (NB + 31) / 32, GA = (NA + 31) / 32;
    const int GBa = (NB + 3) / 4,  GAa = (NA + 3) / 4;

    k_init<<<dim3((NA + 7) / 8), dim3(256), 0, stream>>>(x_a_in, xa, stat_a, NA);
    k_init<<<dim3((NB + 7) / 8), dim3(256), 0, stream>>>(x_b_in, xb, stat_b, NB);

    k_wcvt<<<dim3(1024), dim3(256), 0, stream>>>(pw1, pw2, uw, w1t, w2t, uwt);

    hipMemsetAsync(cnt_b, 0, (size_t)(NB + NA) * sizeof(int), stream);
    k_hist_dual<<<dim3((Eab + Eba + 255) / 256), dim3(256), 0, stream>>>(
        e_ab + Eab, Eab, cnt_b, e_ba + Eba, Eba, cnt_a);
    k_scan_dual<<<dim3(2), dim3(SCAN_T), 0, stream>>>(
        cnt_b, rowp_b, off_b, NB, cnt_a, rowp_a, off_a, NA);
    k_scatter_dual<<<dim3((Eab + Eba + 255) / 256), dim3(256), 0, stream>>>(
        e_ab, e_ab + Eab, Eab, off_b, srcs_ab,
        e_ba, e_ba + Eba, Eba, off_a, srcs_ba);

    for (int l = 0; l < 2; ++l) {
        int t0 = l * 2 + 0;   // conv a->b (dst = b)
        int t1 = l * 2 + 1;   // conv b->a (dst = a)

        k_pred_dual<<<dim3(GB + GA), dim3(256), 0, stream>>>(
            xb, prd_b, NB, GB,
            w1t + (size_t)t0 * 16384, pb1 + t0 * CC, w2t + (size_t)t0 * 16384, pb2 + t0 * CC,
            xa, prd_a, NA,
            w1t + (size_t)t1 * 16384, pb1 + t1 * CC, w2t + (size_t)t1 * 16384, pb2 + t1 * CC);

        k_agg_dual<<<dim3(GBa + GAa), dim3(256), 0, stream>>>(
            rowp_b, srcs_ab, xa, stat_a, prd_b, mgam + t0 * CC, mbet + t0 * CC, agg_b, NB, GBa,
            rowp_a, srcs_ba, xb, stat_b, prd_a, mgam + t1 * CC, mbet + t1 * CC, agg_a, NA);

        k_update_dual<<<dim3(GB + GA), dim3(256), 0, stream>>>(
            xb, agg_b, xb, stat_b, NB, GB,
            uwt + (size_t)t0 * 32768, ubias + t0 * CC, ngam + t0 * CC, nbet + t0 * CC,
            xa, agg_a, xa, stat_a, NA,
            uwt + (size_t)t1 * 32768, ubias + t1 * CC, ngam + t1 * CC, nbet + t1 * CC);
    }

    k_head<<<dim3((out_size + 3) / 4), dim3(256), 0, stream>>>(
        xa, hw, hb, (float*)d_out, out_size);
}

// Round 5
// 241.143 us; speedup vs baseline: 2.7478x; 1.1398x over previous
//
#include <hip/hip_runtime.h>

#define CC 128
#define SCAN_T 1024
#define SCAN_I 4

typedef __attribute__((ext_vector_type(8))) short bf16x8;
typedef __attribute__((ext_vector_type(4))) float f32x4;
#define MFMA16(a, b, c) __builtin_amdgcn_mfma_f32_16x16x32_bf16(a, b, c, 0, 0, 0)

__device__ __forceinline__ float enc_nan(float v) {
    if (v != v) return 0.f;
    if (v > 3.0e38f) return 1.f;
    if (v < -3.0e38f) return -1.f;
    return v;
}

__device__ __forceinline__ ushort f2bf(float x) {
    unsigned u = __builtin_bit_cast(unsigned, x);
    u += 0x7fff + ((u >> 16) & 1);
    return (ushort)(u >> 16);
}
__device__ __forceinline__ float bf2f(ushort h) {
    return __builtin_bit_cast(float, ((unsigned)h) << 16);
}

__device__ __forceinline__ int swz128(int row, int k) { return (row * 128 + k) ^ ((row & 7) << 3); }
__device__ __forceinline__ int swz256(int row, int k) { return (row * 256 + k) ^ ((row & 7) << 3); }

// ---------- init: nan_to_num -> bf16 copy + per-row (sum, sumsq) of rounded ----------
__global__ __launch_bounds__(256)
void k_init(const float* __restrict__ xin, ushort* __restrict__ xbf,
            float2* __restrict__ stat, int N)
{
    int row = blockIdx.x * 8 + (threadIdx.x >> 5);
    int s = threadIdx.x & 31;
    if (row >= N) return;
    float4 v = *reinterpret_cast<const float4*>(xin + (size_t)row * CC + s * 4);
    ushort h0 = f2bf(enc_nan(v.x)), h1 = f2bf(enc_nan(v.y));
    ushort h2 = f2bf(enc_nan(v.z)), h3 = f2bf(enc_nan(v.w));
    ushort4 hv = make_ushort4(h0, h1, h2, h3);
    *reinterpret_cast<ushort4*>(xbf + (size_t)row * CC + s * 4) = hv;
    float r0 = bf2f(h0), r1 = bf2f(h1), r2 = bf2f(h2), r3 = bf2f(h3);
    float sm = (r0 + r1) + (r2 + r3);
    float sq = fmaf(r0, r0, fmaf(r1, r1, fmaf(r2, r2, r3 * r3)));
    #pragma unroll
    for (int m = 1; m < 32; m <<= 1) { sm += __shfl_xor(sm, m); sq += __shfl_xor(sq, m); }
    if (s == 0) stat[row] = make_float2(sm, sq);
}

// ---------- weight convert + transpose to bf16 [col][k] ----------
__global__ __launch_bounds__(256)
void k_wcvt(const float* __restrict__ pw1, const float* __restrict__ pw2,
            const float* __restrict__ uw,
            ushort* __restrict__ w1t, ushort* __restrict__ w2t, ushort* __restrict__ uwt)
{
    int i = blockIdx.x * 256 + threadIdx.x;   // 4 types x 65536
    int t = i >> 16;
    int r = i & 65535;
    if (r < 16384) {
        int k = r >> 7, c = r & 127;
        w1t[(size_t)t * 16384 + c * 128 + k] = f2bf(pw1[(size_t)t * 16384 + k * 128 + c]);
    } else if (r < 32768) {
        int rr = r - 16384;
        int k = rr >> 7, c = rr & 127;
        w2t[(size_t)t * 16384 + c * 128 + k] = f2bf(pw2[(size_t)t * 16384 + k * 128 + c]);
    } else {
        int rr = r - 32768;
        int k = rr >> 7, c = rr & 127;
        uwt[(size_t)t * 32768 + c * 256 + k] = f2bf(uw[(size_t)t * 32768 + k * 128 + c]);
    }
}

// ---------- CSR build (dual) ----------
__global__ __launch_bounds__(256)
void k_hist_dual(const int* __restrict__ dst_b, int Eab, int* __restrict__ cnt_b,
                 const int* __restrict__ dst_a, int Eba, int* __restrict__ cnt_a)
{
    int i = blockIdx.x * 256 + threadIdx.x;
    if (i < Eab) atomicAdd(&cnt_b[dst_b[i]], 1);
    else if (i - Eab < Eba) atomicAdd(&cnt_a[dst_a[i - Eab]], 1);
}

__global__ __launch_bounds__(SCAN_T)
void k_scan_dual(const int* __restrict__ cnt0, int* __restrict__ rowp0, int* __restrict__ off0, int n0,
                 const int* __restrict__ cnt1, int* __restrict__ rowp1, int* __restrict__ off1, int n1)
{
    const int* cnt = (blockIdx.x == 0) ? cnt0 : cnt1;
    int* row_ptr   = (blockIdx.x == 0) ? rowp0 : rowp1;
    int* off       = (blockIdx.x == 0) ? off0 : off1;
    int n          = (blockIdx.x == 0) ? n0 : n1;

    __shared__ int wsum[SCAN_T / 64];
    __shared__ int carry_s;
    const int tid = threadIdx.x, lane = tid & 63, wid = tid >> 6;
    if (tid == 0) carry_s = 0;
    __syncthreads();
    const int chunk = SCAN_T * SCAN_I;
    for (int base = 0; base < n; base += chunk) {
        int i0 = base + tid * SCAN_I;
        int v[SCAN_I];
        int local = 0;
        #pragma unroll
        for (int t = 0; t < SCAN_I; ++t) {
            int i = i0 + t;
            v[t] = (i < n) ? cnt[i] : 0;
            local += v[t];
        }
        int incl = local;
        #pragma unroll
        for (int d = 1; d < 64; d <<= 1) {
            int t = __shfl_up(incl, d);
            if (lane >= d) incl += t;
        }
        if (lane == 63) wsum[wid] = incl;
        __syncthreads();
        if (wid == 0) {
            int wv = (lane < SCAN_T / 64) ? wsum[lane] : 0;
            int winc = wv;
            #pragma unroll
            for (int d = 1; d < SCAN_T / 64; d <<= 1) {
                int t = __shfl_up(winc, d);
                if (lane >= d) winc += t;
            }
            if (lane < SCAN_T / 64) wsum[lane] = winc - wv;
        }
        __syncthreads();
        int carry = carry_s;
        int excl = carry + wsum[wid] + incl - local;
        #pragma unroll
        for (int t = 0; t < SCAN_I; ++t) {
            int i = i0 + t;
            if (i < n) { row_ptr[i] = excl; off[i] = excl; }
            excl += v[t];
        }
        __syncthreads();
        if (tid == SCAN_T - 1) carry_s = carry + wsum[SCAN_T / 64 - 1] + incl;
        __syncthreads();
    }
    if (threadIdx.x == 0) row_ptr[n] = carry_s;
}

__global__ __launch_bounds__(256)
void k_scatter_dual(const int* __restrict__ src_b, const int* __restrict__ dst_b, int Eab,
                    int* __restrict__ off_b, int* __restrict__ srcs_ab,
                    const int* __restrict__ src_a, const int* __restrict__ dst_a, int Eba,
                    int* __restrict__ off_a, int* __restrict__ srcs_ba)
{
    int i = blockIdx.x * 256 + threadIdx.x;
    if (i < Eab) {
        int p = atomicAdd(&off_b[dst_b[i]], 1);
        srcs_ab[p] = src_b[i];
    } else if (i - Eab < Eba) {
        int j = i - Eab;
        int p = atomicAdd(&off_a[dst_a[j]], 1);
        srcs_ba[p] = src_a[j];
    }
}

// ---------- pred = relu(x @ w1 + b1) @ w2 + b2  -> bf16 (32 nodes/block) ----------
__device__ __forceinline__ void pred_body(
    ushort* As, ushort* Hs,
    const ushort* __restrict__ xbf, ushort* __restrict__ pred_bf, int N, int blk,
    const ushort* __restrict__ w1t, const float* __restrict__ b1,
    const ushort* __restrict__ w2t, const float* __restrict__ b2)
{
    const int tid = threadIdx.x;
    const int base = blk * 32;

    {   // stage x_bf -> As (swizzled), 2x ushort8 per thread
        int row = tid >> 3, k0 = (tid & 7) << 4;
        int node = base + row;
        bf16x8 v0 = {}, v1 = {};
        if (node < N) {
            v0 = *reinterpret_cast<const bf16x8*>(xbf + (size_t)node * CC + k0);
            v1 = *reinterpret_cast<const bf16x8*>(xbf + (size_t)node * CC + k0 + 8);
        }
        *reinterpret_cast<bf16x8*>(&As[swz128(row, k0)])     = v0;
        *reinterpret_cast<bf16x8*>(&As[swz128(row, k0 + 8)]) = v1;
    }
    __syncthreads();

    const int w = tid >> 6, l = tid & 63;
    const int lr = l & 15, lg = l >> 4;

    f32x4 acc[2][2] = {};
    for (int kb = 0; kb < 4; ++kb) {
        int k = kb * 32 + lg * 8;
        bf16x8 a0 = *reinterpret_cast<const bf16x8*>(&As[swz128(lr, k)]);
        bf16x8 a1 = *reinterpret_cast<const bf16x8*>(&As[swz128(lr + 16, k)]);
        bf16x8 b0 = *reinterpret_cast<const bf16x8*>(&w1t[(size_t)(w * 32 + lr) * 128 + k]);
        bf16x8 b1v = *reinterpret_cast<const bf16x8*>(&w1t[(size_t)(w * 32 + 16 + lr) * 128 + k]);
        acc[0][0] = MFMA16(a0, b0, acc[0][0]);
        acc[0][1] = MFMA16(a0, b1v, acc[0][1]);
        acc[1][0] = MFMA16(a1, b0, acc[1][0]);
        acc[1][1] = MFMA16(a1, b1v, acc[1][1]);
    }
    {
        float bc[2] = { b1[w * 32 + lr], b1[w * 32 + 16 + lr] };
        #pragma unroll
        for (int mi = 0; mi < 2; ++mi)
            #pragma unroll
            for (int ni = 0; ni < 2; ++ni) {
                int col = w * 32 + ni * 16 + lr;
                #pragma unroll
                for (int j = 0; j < 4; ++j) {
                    int row = mi * 16 + lg * 4 + j;
                    Hs[swz128(row, col)] = f2bf(fmaxf(acc[mi][ni][j] + bc[ni], 0.f));
                }
            }
    }
    __syncthreads();

    f32x4 acc2[2][2] = {};
    for (int kb = 0; kb < 4; ++kb) {
        int k = kb * 32 + lg * 8;
        bf16x8 a0 = *reinterpret_cast<const bf16x8*>(&Hs[swz128(lr, k)]);
        bf16x8 a1 = *reinterpret_cast<const bf16x8*>(&Hs[swz128(lr + 16, k)]);
        bf16x8 b0 = *reinterpret_cast<const bf16x8*>(&w2t[(size_t)(w * 32 + lr) * 128 + k]);
        bf16x8 b1v = *reinterpret_cast<const bf16x8*>(&w2t[(size_t)(w * 32 + 16 + lr) * 128 + k]);
        acc2[0][0] = MFMA16(a0, b0, acc2[0][0]);
        acc2[0][1] = MFMA16(a0, b1v, acc2[0][1]);
        acc2[1][0] = MFMA16(a1, b0, acc2[1][0]);
        acc2[1][1] = MFMA16(a1, b1v, acc2[1][1]);
    }
    {
        float bc[2] = { b2[w * 32 + lr], b2[w * 32 + 16 + lr] };
        #pragma unroll
        for (int mi = 0; mi < 2; ++mi)
            #pragma unroll
            for (int ni = 0; ni < 2; ++ni) {
                int col = w * 32 + ni * 16 + lr;
                #pragma unroll
                for (int j = 0; j < 4; ++j) {
                    int row = mi * 16 + lg * 4 + j;
                    int node = base + row;
                    if (node < N)
                        pred_bf[(size_t)node * CC + col] = f2bf(acc2[mi][ni][j] + bc[ni]);
                }
            }
    }
}

__global__ __launch_bounds__(256)
void k_pred_dual(const ushort* __restrict__ xb, ushort* __restrict__ prd_b, int NB, int GB,
                 const ushort* __restrict__ w1t0, const float* __restrict__ b10,
                 const ushort* __restrict__ w2t0, const float* __restrict__ b20,
                 const ushort* __restrict__ xa, ushort* __restrict__ prd_a, int NA,
                 const ushort* __restrict__ w1t1, const float* __restrict__ b11,
                 const ushort* __restrict__ w2t1, const float* __restrict__ b21)
{
    __shared__ __align__(16) ushort As[32 * 128];
    __shared__ __align__(16) ushort Hs[32 * 128];
    if ((int)blockIdx.x < GB)
        pred_body(As, Hs, xb, prd_b, NB, blockIdx.x, w1t0, b10, w2t0, b20);
    else
        pred_body(As, Hs, xa, prd_a, NA, blockIdx.x - GB, w1t1, b11, w2t1, b21);
}

// ---------- gather aggregation: wave = dst node, quarters = 4 edges in flight ----------
__device__ __forceinline__ void agg_body(
    const int* __restrict__ rowp, const int* __restrict__ srcs,
    const ushort* __restrict__ xsrc, const float2* __restrict__ statx,
    const ushort* __restrict__ pred_bf, const float* __restrict__ g,
    const float* __restrict__ be, ushort* __restrict__ agg_bf, int N, int blk)
{
    const int wid = threadIdx.x >> 6;
    const int lane = threadIdx.x & 63;
    const int d = blk * 4 + wid;
    if (d >= N) return;
    const int quarter = lane >> 4;
    const int c = (lane & 15) * 8;
    const int jb = rowp[d], je = rowp[d + 1];
    const int deg = je - jb;

    bf16x8 prb = *reinterpret_cast<const bf16x8*>(pred_bf + (size_t)d * CC + c);
    float pr[8];
    #pragma unroll
    for (int i = 0; i < 8; ++i) pr[i] = bf2f((ushort)prb[i]);

    // per-dst pred stats, reduced within each 16-lane quarter (all quarters identical)
    float sp = 0.f, qp = 0.f;
    #pragma unroll
    for (int i = 0; i < 8; ++i) { sp += pr[i]; qp = fmaf(pr[i], pr[i], qp); }
    #pragma unroll
    for (int m = 1; m < 16; m <<= 1) { sp += __shfl_xor(sp, m); qp += __shfl_xor(qp, m); }

    float a[8] = {};
    float rsum = 0.f, cmsum = 0.f;
    for (int j = jb + quarter; j < je; j += 4) {
        const int sidx = srcs[j];
        bf16x8 xb_ = *reinterpret_cast<const bf16x8*>(xsrc + (size_t)sidx * CC + c);
        const float2 st = statx[sidx];
        float xj[8];
        #pragma unroll
        for (int i = 0; i < 8; ++i) xj[i] = bf2f((ushort)xb_[i]);
        float dot = 0.f;
        #pragma unroll
        for (int i = 0; i < 8; ++i) dot = fmaf(xj[i], pr[i], dot);
        #pragma unroll
        for (int m = 1; m < 16; m <<= 1) dot += __shfl_xor(dot, m);
        const float mean = (st.x - sp) * (1.f / 128.f);
        const float var = fmaf(-2.f, dot, st.y + qp) * (1.f / 128.f) - mean * mean;
        const float r = rsqrtf(var + 1e-5f);
        rsum += r;
        cmsum = fmaf(mean, r, cmsum);
        #pragma unroll
        for (int i = 0; i < 8; ++i) a[i] = fmaf(xj[i], r, a[i]);
    }
    // combine quarters
    #pragma unroll
    for (int i = 0; i < 8; ++i) { a[i] += __shfl_xor(a[i], 16); a[i] += __shfl_xor(a[i], 32); }
    rsum += __shfl_xor(rsum, 16);  rsum += __shfl_xor(rsum, 32);
    cmsum += __shfl_xor(cmsum, 16); cmsum += __shfl_xor(cmsum, 32);

    if (quarter == 0) {
        ushort o8[8];
        if (deg > 0) {
            const float inv = 1.f / (float)deg;
            const float4 g0 = *reinterpret_cast<const float4*>(g + c);
            const float4 g1 = *reinterpret_cast<const float4*>(g + c + 4);
            const float4 b0 = *reinterpret_cast<const float4*>(be + c);
            const float4 b1 = *reinterpret_cast<const float4*>(be + c + 4);
            const float gv[8] = { g0.x, g0.y, g0.z, g0.w, g1.x, g1.y, g1.z, g1.w };
            const float bv[8] = { b0.x, b0.y, b0.z, b0.w, b1.x, b1.y, b1.z, b1.w };
            #pragma unroll
            for (int i = 0; i < 8; ++i)
                o8[i] = f2bf(fmaf((a[i] - pr[i] * rsum - cmsum) * inv, gv[i], bv[i]));
        } else {
            #pragma unroll
            for (int i = 0; i < 8; ++i) o8[i] = 0;
        }
        *reinterpret_cast<bf16x8*>(agg_bf + (size_t)d * CC + c) =
            *reinterpret_cast<bf16x8*>(&o8[0]);
    }
}

__global__ __launch_bounds__(256)
void k_agg_dual(const int* __restrict__ rowp_b, const int* __restrict__ srcs_ab,
                const ushort* __restrict__ xa, const float2* __restrict__ stat_a,
                const ushort* __restrict__ prd_b, const float* __restrict__ g0,
                const float* __restrict__ be0, ushort* __restrict__ agg_b, int NB, int GBa,
                const int* __restrict__ rowp_a, const int* __restrict__ srcs_ba,
                const ushort* __restrict__ xb, const float2* __restrict__ stat_b,
                const ushort* __restrict__ prd_a, const float* __restrict__ g1,
                const float* __restrict__ be1, ushort* __restrict__ agg_a, int NA)
{
    if ((int)blockIdx.x < GBa)
        agg_body(rowp_b, srcs_ab, xa, stat_a, prd_b, g0, be0, agg_b, NB, blockIdx.x);
    else
        agg_body(rowp_a, srcs_ba, xb, stat_b, prd_a, g1, be1, agg_a, NA, blockIdx.x - GBa);
}

// ---------- x = relu(LN(relu(concat(x, agg) @ uw + ub))) + stats + optional head ----------
__device__ __forceinline__ void update_body(
    ushort* As, float (*os)[CC + 4],
    const ushort* __restrict__ xbf, const ushort* __restrict__ agg_bf,
    ushort* __restrict__ xout, float2* __restrict__ statOut, int N, int blk,
    const ushort* __restrict__ uwt, const float* __restrict__ ub,
    const float* __restrict__ ng, const float* __restrict__ nb,
    const float* __restrict__ hw, const float* __restrict__ hb,
    float* __restrict__ hout, int headS)
{
    const int tid = threadIdx.x;
    const int base = blk * 32;

    {   // stage concat(x_bf, agg_bf) -> As (swizzled)
        int row = tid >> 3, k0 = (tid & 7) << 4;
        int node = base + row;
        bf16x8 v0 = {}, v1 = {}, v2 = {}, v3 = {};
        if (node < N) {
            v0 = *reinterpret_cast<const bf16x8*>(xbf + (size_t)node * CC + k0);
            v1 = *reinterpret_cast<const bf16x8*>(xbf + (size_t)node * CC + k0 + 8);
            v2 = *reinterpret_cast<const bf16x8*>(agg_bf + (size_t)node * CC + k0);
            v3 = *reinterpret_cast<const bf16x8*>(agg_bf + (size_t)node * CC + k0 + 8);
        }
        *reinterpret_cast<bf16x8*>(&As[swz256(row, k0)])           = v0;
        *reinterpret_cast<bf16x8*>(&As[swz256(row, k0 + 8)])       = v1;
        *reinterpret_cast<bf16x8*>(&As[swz256(row, 128 + k0)])     = v2;
        *reinterpret_cast<bf16x8*>(&As[swz256(row, 128 + k0 + 8)]) = v3;
    }
    __syncthreads();

    const int w = tid >> 6, l = tid & 63;
    const int lr = l & 15, lg = l >> 4;

    f32x4 acc[2][2] = {};
    for (int kb = 0; kb < 8; ++kb) {
        int k = kb * 32 + lg * 8;
        bf16x8 a0 = *reinterpret_cast<const bf16x8*>(&As[swz256(lr, k)]);
        bf16x8 a1 = *reinterpret_cast<const bf16x8*>(&As[swz256(lr + 16, k)]);
        bf16x8 b0 = *reinterpret_cast<const bf16x8*>(&uwt[(size_t)(w * 32 + lr) * 256 + k]);
        bf16x8 b1v = *reinterpret_cast<const bf16x8*>(&uwt[(size_t)(w * 32 + 16 + lr) * 256 + k]);
        acc[0][0] = MFMA16(a0, b0, acc[0][0]);
        acc[0][1] = MFMA16(a0, b1v, acc[0][1]);
        acc[1][0] = MFMA16(a1, b0, acc[1][0]);
        acc[1][1] = MFMA16(a1, b1v, acc[1][1]);
    }
    {
        float bc[2] = { ub[w * 32 + lr], ub[w * 32 + 16 + lr] };
        #pragma unroll
        for (int mi = 0; mi < 2; ++mi)
            #pragma unroll
            for (int ni = 0; ni < 2; ++ni) {
                int col = w * 32 + ni * 16 + lr;
                #pragma unroll
                for (int j = 0; j < 4; ++j) {
                    int row = mi * 16 + lg * 4 + j;
                    os[row][col] = fmaxf(acc[mi][ni][j] + bc[ni], 0.f);
                }
            }
    }
    __syncthreads();

    // node LayerNorm + relu + stats (+head); 8 lanes/node, 16 channels/lane
    const int lane = tid & 63;
    const int nl = (tid >> 6) * 8 + (lane >> 3);
    const int cl = lane & 7;
    float vals[16];
    float sm = 0.f, sq = 0.f;
    #pragma unroll
    for (int t = 0; t < 16; ++t) {
        float u = os[nl][cl + 8 * t];
        vals[t] = u; sm += u; sq = fmaf(u, u, sq);
    }
    #pragma unroll
    for (int m = 1; m < 8; m <<= 1) { sm += __shfl_xor(sm, m); sq += __shfl_xor(sq, m); }
    float mean = sm * (1.f / 128.f);
    float var = sq * (1.f / 128.f) - mean * mean;
    float r = rsqrtf(var + 1e-5f);
    int node = base + nl;
    if (node < N) {
        float so = 0.f, sqo = 0.f, hsum = 0.f;
        bool doHead = (node < headS);
        #pragma unroll
        for (int t = 0; t < 16; ++t) {
            int cch = cl + 8 * t;
            float o = fmaxf(fmaf((vals[t] - mean) * r, ng[cch], nb[cch]), 0.f);
            ushort ob = f2bf(o);
            xout[(size_t)node * CC + cch] = ob;
            float orr = bf2f(ob);
            so += orr; sqo = fmaf(orr, orr, sqo);
            if (doHead) hsum = fmaf(o, hw[cch], hsum);
        }
        #pragma unroll
        for (int m = 1; m < 8; m <<= 1) { so += __shfl_xor(so, m); sqo += __shfl_xor(sqo, m); }
        if (doHead) {
            #pragma unroll
            for (int m = 1; m < 8; m <<= 1) hsum += __shfl_xor(hsum, m);
            if (cl == 0) hout[node] = hsum + hb[0];
        }
        if (cl == 0) statOut[node] = make_float2(so, sqo);
    }
}

__global__ __launch_bounds__(256)
void k_update_dual(const ushort* __restrict__ xb, const ushort* __restrict__ agg_b,
                   ushort* __restrict__ xb_o, float2* __restrict__ stat_b, int NB, int GB,
                   const ushort* __restrict__ uwt0, const float* __restrict__ ub0,
                   const float* __restrict__ ng0, const float* __restrict__ nb0,
                   const ushort* __restrict__ xa, const ushort* __restrict__ agg_a,
                   ushort* __restrict__ xa_o, float2* __restrict__ stat_a, int NA,
                   const ushort* __restrict__ uwt1, const float* __restrict__ ub1,
                   const float* __restrict__ ng1, const float* __restrict__ nb1,
                   const float* __restrict__ hw, const float* __restrict__ hb,
                   float* __restrict__ hout, int headS)
{
    __shared__ __align__(16) ushort As[32 * 256];
    __shared__ float os[32][CC + 4];
    if ((int)blockIdx.x < GB)
        update_body(As, os, xb, agg_b, xb_o, stat_b, NB, blockIdx.x,
                    uwt0, ub0, ng0, nb0, hw, hb, hout, 0);
    else
        update_body(As, os, xa, agg_a, xa_o, stat_a, NA, blockIdx.x - GB,
                    uwt1, ub1, ng1, nb1, hw, hb, hout, headS);
}

extern "C" void kernel_launch(void* const* d_in, const int* in_sizes, int n_in,
                              void* d_out, int out_size, void* d_ws, size_t ws_size,
                              hipStream_t stream)
{
    const float* x_a_in = (const float*)d_in[0];
    const float* x_b_in = (const float*)d_in[1];
    const int*   e_ab   = (const int*)d_in[2];
    const int*   e_ba   = (const int*)d_in[3];
    const float* pw1    = (const float*)d_in[4];
    const float* pb1    = (const float*)d_in[5];
    const float* pw2    = (const float*)d_in[6];
    const float* pb2    = (const float*)d_in[7];
    const float* mgam   = (const float*)d_in[8];
    const float* mbet   = (const float*)d_in[9];
    const float* uw     = (const float*)d_in[10];
    const float* ubias  = (const float*)d_in[11];
    const float* ngam   = (const float*)d_in[12];
    const float* nbet   = (const float*)d_in[13];
    const float* hw     = (const float*)d_in[14];
    const float* hb     = (const float*)d_in[15];

    const int NA  = in_sizes[0] / CC;
    const int NB  = in_sizes[1] / CC;
    const int Eab = in_sizes[2] / 2;
    const int Eba = in_sizes[3] / 2;

    float* ws = (float*)d_ws;
    size_t off = 0;  // in floats
    ushort* xa    = (ushort*)(ws + off); off += (size_t)NA * CC / 2;
    ushort* xb    = (ushort*)(ws + off); off += (size_t)NB * CC / 2;
    ushort* prd_b = (ushort*)(ws + off); off += (size_t)NB * CC / 2;
    ushort* prd_a = (ushort*)(ws + off); off += (size_t)NA * CC / 2;
    ushort* agg_a = (ushort*)(ws + off); off += (size_t)NA * CC / 2;
    ushort* agg_b = (ushort*)(ws + off); off += (size_t)NB * CC / 2;
    float2* stat_a = (float2*)(ws + off); off += (size_t)NA * 2;
    float2* stat_b = (float2*)(ws + off); off += (size_t)NB * 2;
    ushort* w1t  = (ushort*)(ws + off); off += 4 * 16384 / 2;
    ushort* w2t  = (ushort*)(ws + off); off += 4 * 16384 / 2;
    ushort* uwt  = (ushort*)(ws + off); off += 4 * 32768 / 2;
    int* iw = (int*)(ws + off);
    size_t ioff = 0;
    int* cnt_b   = iw + ioff; ioff += NB;
    int* cnt_a   = iw + ioff; ioff += NA;
    int* rowp_b  = iw + ioff; ioff += NB + 1;
    int* rowp_a  = iw + ioff; ioff += NA + 1;
    int* off_b   = iw + ioff; ioff += NB;
    int* off_a   = iw + ioff; ioff += NA;
    int* srcs_ab = iw + ioff; ioff += Eab;
    int* srcs_ba = iw + ioff; ioff += Eba;

    const int GB  = (NB + 31) / 32, GA = (NA + 31) / 32;
    const int GBa = (NB + 3) / 4,  GAa = (NA + 3) / 4;

    k_init<<<dim3((NA + 7) / 8), dim3(256), 0, stream>>>(x_a_in, xa, stat_a, NA);
    k_init<<<dim3((NB + 7) / 8), dim3(256), 0, stream>>>(x_b_in, xb, stat_b, NB);

    k_wcvt<<<dim3(1024), dim3(256), 0, stream>>>(pw1, pw2, uw, w1t, w2t, uwt);

    hipMemsetAsync(cnt_b, 0, (size_t)(NB + NA) * sizeof(int), stream);
    k_hist_dual<<<dim3((Eab + Eba + 255) / 256), dim3(256), 0, stream>>>(
        e_ab + Eab, Eab, cnt_b, e_ba + Eba, Eba, cnt_a);
    k_scan_dual<<<dim3(2), dim3(SCAN_T), 0, stream>>>(
        cnt_b, rowp_b, off_b, NB, cnt_a, rowp_a, off_a, NA);
    k_scatter_dual<<<dim3((Eab + Eba + 255) / 256), dim3(256), 0, stream>>>(
        e_ab, e_ab + Eab, Eab, off_b, srcs_ab,
        e_ba, e_ba + Eba, Eba, off_a, srcs_ba);

    for (int l = 0; l < 2; ++l) {
        int t0 = l * 2 + 0;   // conv a->b (dst = b)
        int t1 = l * 2 + 1;   // conv b->a (dst = a)
        int headS = (l == 1) ? out_size : 0;

        k_pred_dual<<<dim3(GB + GA), dim3(256), 0, stream>>>(
            xb, prd_b, NB, GB,
            w1t + (size_t)t0 * 16384, pb1 + t0 * CC, w2t + (size_t)t0 * 16384, pb2 + t0 * CC,
            xa, prd_a, NA,
            w1t + (size_t)t1 * 16384, pb1 + t1 * CC, w2t + (size_t)t1 * 16384, pb2 + t1 * CC);

        k_agg_dual<<<dim3(GBa + GAa), dim3(256), 0, stream>>>(
            rowp_b, srcs_ab, xa, stat_a, prd_b, mgam + t0 * CC, mbet + t0 * CC, agg_b, NB, GBa,
            rowp_a, srcs_ba, xb, stat_b, prd_a, mgam + t1 * CC, mbet + t1 * CC, agg_a, NA);

        k_update_dual<<<dim3(GB + GA), dim3(256), 0, stream>>>(
            xb, agg_b, xb, stat_b, NB, GB,
            uwt + (size_t)t0 * 32768, ubias + t0 * CC, ngam + t0 * CC, nbet + t0 * CC,
            xa, agg_a, xa, stat_a, NA,
            uwt + (size_t)t1 * 32768, ubias + t1 * CC, ngam + t1 * CC, nbet + t1 * CC,
            hw, hb, (float*)d_out, headS);
    }
}

// Round 6
// 228.275 us; speedup vs baseline: 2.9027x; 1.0564x over previous
//
#include <hip/hip_runtime.h>

#define CC 128
#define SCAN_T 1024
#define SCAN_I 4

typedef __attribute__((ext_vector_type(8))) short bf16x8;
typedef __attribute__((ext_vector_type(4))) float f32x4;
#define MFMA16(a, b, c) __builtin_amdgcn_mfma_f32_16x16x32_bf16(a, b, c, 0, 0, 0)

__device__ __forceinline__ float enc_nan(float v) {
    if (v != v) return 0.f;
    if (v > 3.0e38f) return 1.f;
    if (v < -3.0e38f) return -1.f;
    return v;
}

__device__ __forceinline__ ushort f2bf(float x) {
    unsigned u = __builtin_bit_cast(unsigned, x);
    u += 0x7fff + ((u >> 16) & 1);
    return (ushort)(u >> 16);
}
__device__ __forceinline__ float bf2f(ushort h) {
    return __builtin_bit_cast(float, ((unsigned)h) << 16);
}

__device__ __forceinline__ int swz128(int row, int k) { return (row * 128 + k) ^ ((row & 7) << 3); }

// ---------- init (dual): nan_to_num -> bf16 + per-row stats ----------
__global__ __launch_bounds__(256)
void k_init_dual(const float* __restrict__ xa_in, ushort* __restrict__ xa,
                 float2* __restrict__ stat_a, int NA,
                 const float* __restrict__ xb_in, ushort* __restrict__ xb,
                 float2* __restrict__ stat_b, int NB)
{
    int row = blockIdx.x * 8 + (threadIdx.x >> 5);
    int s = threadIdx.x & 31;
    const float* xin; ushort* xo; float2* st;
    if (row < NA) { xin = xa_in; xo = xa; st = stat_a; }
    else {
        row -= NA;
        if (row >= NB) return;
        xin = xb_in; xo = xb; st = stat_b;
    }
    float4 v = *reinterpret_cast<const float4*>(xin + (size_t)row * CC + s * 4);
    ushort h0 = f2bf(enc_nan(v.x)), h1 = f2bf(enc_nan(v.y));
    ushort h2 = f2bf(enc_nan(v.z)), h3 = f2bf(enc_nan(v.w));
    *reinterpret_cast<ushort4*>(xo + (size_t)row * CC + s * 4) = make_ushort4(h0, h1, h2, h3);
    float r0 = bf2f(h0), r1 = bf2f(h1), r2 = bf2f(h2), r3 = bf2f(h3);
    float sm = (r0 + r1) + (r2 + r3);
    float sq = fmaf(r0, r0, fmaf(r1, r1, fmaf(r2, r2, r3 * r3)));
    #pragma unroll
    for (int m = 1; m < 32; m <<= 1) { sm += __shfl_xor(sm, m); sq += __shfl_xor(sq, m); }
    if (s == 0) st[row] = make_float2(sm, sq);
}

// ---------- weight convert + transpose to bf16 [col][k] ----------
__global__ __launch_bounds__(256)
void k_wcvt(const float* __restrict__ pw1, const float* __restrict__ pw2,
            const float* __restrict__ uw,
            ushort* __restrict__ w1t, ushort* __restrict__ w2t, ushort* __restrict__ uwt)
{
    int i = blockIdx.x * 256 + threadIdx.x;   // 4 types x 65536
    int t = i >> 16;
    int r = i & 65535;
    if (r < 16384) {
        int k = r >> 7, c = r & 127;
        w1t[(size_t)t * 16384 + c * 128 + k] = f2bf(pw1[(size_t)t * 16384 + k * 128 + c]);
    } else if (r < 32768) {
        int rr = r - 16384;
        int k = rr >> 7, c = rr & 127;
        w2t[(size_t)t * 16384 + c * 128 + k] = f2bf(pw2[(size_t)t * 16384 + k * 128 + c]);
    } else {
        int rr = r - 32768;
        int k = rr >> 7, c = rr & 127;
        uwt[(size_t)t * 32768 + c * 256 + k] = f2bf(uw[(size_t)t * 32768 + k * 128 + c]);
    }
}

// ---------- CSR build (dual) ----------
__global__ __launch_bounds__(256)
void k_hist_dual(const int* __restrict__ dst_b, int Eab, int* __restrict__ cnt_b,
                 const int* __restrict__ dst_a, int Eba, int* __restrict__ cnt_a)
{
    int i = blockIdx.x * 256 + threadIdx.x;
    if (i < Eab) atomicAdd(&cnt_b[dst_b[i]], 1);
    else if (i - Eab < Eba) atomicAdd(&cnt_a[dst_a[i - Eab]], 1);
}

__global__ __launch_bounds__(SCAN_T)
void k_scan_dual(const int* __restrict__ cnt0, int* __restrict__ rowp0, int* __restrict__ off0, int n0,
                 const int* __restrict__ cnt1, int* __restrict__ rowp1, int* __restrict__ off1, int n1)
{
    const int* cnt = (blockIdx.x == 0) ? cnt0 : cnt1;
    int* row_ptr   = (blockIdx.x == 0) ? rowp0 : rowp1;
    int* off       = (blockIdx.x == 0) ? off0 : off1;
    int n          = (blockIdx.x == 0) ? n0 : n1;

    __shared__ int wsum[SCAN_T / 64];
    __shared__ int carry_s;
    const int tid = threadIdx.x, lane = tid & 63, wid = tid >> 6;
    if (tid == 0) carry_s = 0;
    __syncthreads();
    const int chunk = SCAN_T * SCAN_I;
    for (int base = 0; base < n; base += chunk) {
        int i0 = base + tid * SCAN_I;
        int v[SCAN_I];
        int local = 0;
        #pragma unroll
        for (int t = 0; t < SCAN_I; ++t) {
            int i = i0 + t;
            v[t] = (i < n) ? cnt[i] : 0;
            local += v[t];
        }
        int incl = local;
        #pragma unroll
        for (int d = 1; d < 64; d <<= 1) {
            int t = __shfl_up(incl, d);
            if (lane >= d) incl += t;
        }
        if (lane == 63) wsum[wid] = incl;
        __syncthreads();
        if (wid == 0) {
            int wv = (lane < SCAN_T / 64) ? wsum[lane] : 0;
            int winc = wv;
            #pragma unroll
            for (int d = 1; d < SCAN_T / 64; d <<= 1) {
                int t = __shfl_up(winc, d);
                if (lane >= d) winc += t;
            }
            if (lane < SCAN_T / 64) wsum[lane] = winc - wv;
        }
        __syncthreads();
        int carry = carry_s;
        int excl = carry + wsum[wid] + incl - local;
        #pragma unroll
        for (int t = 0; t < SCAN_I; ++t) {
            int i = i0 + t;
            if (i < n) { row_ptr[i] = excl; off[i] = excl; }
            excl += v[t];
        }
        __syncthreads();
        if (tid == SCAN_T - 1) carry_s = carry + wsum[SCAN_T / 64 - 1] + incl;
        __syncthreads();
    }
    if (threadIdx.x == 0) row_ptr[n] = carry_s;
}

__global__ __launch_bounds__(256)
void k_scatter_dual(const int* __restrict__ src_b, const int* __restrict__ dst_b, int Eab,
                    int* __restrict__ off_b, int* __restrict__ srcs_ab,
                    const int* __restrict__ src_a, const int* __restrict__ dst_a, int Eba,
                    int* __restrict__ off_a, int* __restrict__ srcs_ba)
{
    int i = blockIdx.x * 256 + threadIdx.x;
    if (i < Eab) {
        int p = atomicAdd(&off_b[dst_b[i]], 1);
        srcs_ab[p] = src_b[i];
    } else if (i - Eab < Eba) {
        int j = i - Eab;
        int p = atomicAdd(&off_a[dst_a[j]], 1);
        srcs_ba[p] = src_a[j];
    }
}

// ---------- fully fused conv: pred-MLP -> gather-LN-agg -> update-GEMM -> node-LN ----------
__device__ __forceinline__ void layer_body(
    char* smem,
    const ushort* __restrict__ xdst, const ushort* __restrict__ xsrc,
    const float2* __restrict__ stat_src,
    const int* __restrict__ rowp, const int* __restrict__ srcs,
    const ushort* __restrict__ w1t, const float* __restrict__ b1,
    const ushort* __restrict__ w2t, const float* __restrict__ b2,
    const float* __restrict__ mg, const float* __restrict__ mbt,
    const ushort* __restrict__ uwt, const float* __restrict__ ub,
    const float* __restrict__ ng, const float* __restrict__ nb,
    ushort* __restrict__ xout, float2* __restrict__ statOut, int N, int blk,
    const float* __restrict__ hw, const float* __restrict__ hb,
    float* __restrict__ hout, int headS)
{
    ushort* As = (ushort*)smem;              // 32x128 bf16, swizzled (x_dst)
    ushort* Hs = (ushort*)(smem + 8192);     // 32x128 bf16, swizzled (relu(h), then agg)
    ushort* P  = (ushort*)(smem + 16384);    // 32x128 bf16, linear (pred)
    float (*os)[CC + 4] = (float(*)[CC + 4])(smem + 8192);  // overlays Hs+P after update GEMM

    const int tid = threadIdx.x;
    const int base = blk * 32;

    {   // stage x_dst -> As (swizzled)
        int row = tid >> 3, k0 = (tid & 7) << 4;
        int node = base + row;
        bf16x8 v0 = {}, v1 = {};
        if (node < N) {
            v0 = *reinterpret_cast<const bf16x8*>(xdst + (size_t)node * CC + k0);
            v1 = *reinterpret_cast<const bf16x8*>(xdst + (size_t)node * CC + k0 + 8);
        }
        *reinterpret_cast<bf16x8*>(&As[swz128(row, k0)])     = v0;
        *reinterpret_cast<bf16x8*>(&As[swz128(row, k0 + 8)]) = v1;
    }
    __syncthreads();

    const int w = tid >> 6, l = tid & 63;
    const int lr = l & 15, lg = l >> 4;

    // pred GEMM1: Hs = relu(As @ w1 + b1)
    {
        f32x4 acc[2][2] = {};
        for (int kb = 0; kb < 4; ++kb) {
            int k = kb * 32 + lg * 8;
            bf16x8 a0 = *reinterpret_cast<const bf16x8*>(&As[swz128(lr, k)]);
            bf16x8 a1 = *reinterpret_cast<const bf16x8*>(&As[swz128(lr + 16, k)]);
            bf16x8 b0 = *reinterpret_cast<const bf16x8*>(&w1t[(size_t)(w * 32 + lr) * 128 + k]);
            bf16x8 b1v = *reinterpret_cast<const bf16x8*>(&w1t[(size_t)(w * 32 + 16 + lr) * 128 + k]);
            acc[0][0] = MFMA16(a0, b0, acc[0][0]);
            acc[0][1] = MFMA16(a0, b1v, acc[0][1]);
            acc[1][0] = MFMA16(a1, b0, acc[1][0]);
            acc[1][1] = MFMA16(a1, b1v, acc[1][1]);
        }
        float bc[2] = { b1[w * 32 + lr], b1[w * 32 + 16 + lr] };
        #pragma unroll
        for (int mi = 0; mi < 2; ++mi)
            #pragma unroll
            for (int ni = 0; ni < 2; ++ni) {
                int col = w * 32 + ni * 16 + lr;
                #pragma unroll
                for (int j = 0; j < 4; ++j) {
                    int row = mi * 16 + lg * 4 + j;
                    Hs[swz128(row, col)] = f2bf(fmaxf(acc[mi][ni][j] + bc[ni], 0.f));
                }
            }
    }
    __syncthreads();

    // pred GEMM2: P = Hs @ w2 + b2  (linear layout)
    {
        f32x4 acc[2][2] = {};
        for (int kb = 0; kb < 4; ++kb) {
            int k = kb * 32 + lg * 8;
            bf16x8 a0 = *reinterpret_cast<const bf16x8*>(&Hs[swz128(lr, k)]);
            bf16x8 a1 = *reinterpret_cast<const bf16x8*>(&Hs[swz128(lr + 16, k)]);
            bf16x8 b0 = *reinterpret_cast<const bf16x8*>(&w2t[(size_t)(w * 32 + lr) * 128 + k]);
            bf16x8 b1v = *reinterpret_cast<const bf16x8*>(&w2t[(size_t)(w * 32 + 16 + lr) * 128 + k]);
            acc[0][0] = MFMA16(a0, b0, acc[0][0]);
            acc[0][1] = MFMA16(a0, b1v, acc[0][1]);
            acc[1][0] = MFMA16(a1, b0, acc[1][0]);
            acc[1][1] = MFMA16(a1, b1v, acc[1][1]);
        }
        float bc[2] = { b2[w * 32 + lr], b2[w * 32 + 16 + lr] };
        #pragma unroll
        for (int mi = 0; mi < 2; ++mi)
            #pragma unroll
            for (int ni = 0; ni < 2; ++ni) {
                int col = w * 32 + ni * 16 + lr;
                #pragma unroll
                for (int j = 0; j < 4; ++j) {
                    int row = mi * 16 + lg * 4 + j;
                    P[row * CC + col] = f2bf(acc[mi][ni][j] + bc[ni]);
                }
            }
    }
    __syncthreads();

    // agg phase: wave w handles nodes w*8..w*8+7; quarter-wave = 4 edges in flight
    {
        const int quarter = l >> 4;
        const int c = (l & 15) * 8;
        const float4 g0 = *reinterpret_cast<const float4*>(mg + c);
        const float4 g1 = *reinterpret_cast<const float4*>(mg + c + 4);
        const float4 e0 = *reinterpret_cast<const float4*>(mbt + c);
        const float4 e1 = *reinterpret_cast<const float4*>(mbt + c + 4);
        const float gv[8] = { g0.x, g0.y, g0.z, g0.w, g1.x, g1.y, g1.z, g1.w };
        const float bv[8] = { e0.x, e0.y, e0.z, e0.w, e1.x, e1.y, e1.z, e1.w };
        for (int i = 0; i < 8; ++i) {
            const int nl_ = w * 8 + i;
            const int d = base + nl_;
            if (d >= N) break;
            bf16x8 prb = *reinterpret_cast<const bf16x8*>(&P[nl_ * CC + c]);
            float pr[8];
            #pragma unroll
            for (int q = 0; q < 8; ++q) pr[q] = bf2f((ushort)prb[q]);
            float sp = 0.f, qp = 0.f;
            #pragma unroll
            for (int q = 0; q < 8; ++q) { sp += pr[q]; qp = fmaf(pr[q], pr[q], qp); }
            #pragma unroll
            for (int m = 1; m < 16; m <<= 1) { sp += __shfl_xor(sp, m); qp += __shfl_xor(qp, m); }
            const int jb = rowp[d], je = rowp[d + 1];
            const int deg = je - jb;
            float a[8] = {};
            float rsum = 0.f, cmsum = 0.f;
            for (int j = jb + quarter; j < je; j += 4) {
                const int sidx = srcs[j];
                bf16x8 xb_ = *reinterpret_cast<const bf16x8*>(xsrc + (size_t)sidx * CC + c);
                const float2 st = stat_src[sidx];
                float xj[8];
                #pragma unroll
                for (int q = 0; q < 8; ++q) xj[q] = bf2f((ushort)xb_[q]);
                float dot = 0.f;
                #pragma unroll
                for (int q = 0; q < 8; ++q) dot = fmaf(xj[q], pr[q], dot);
                #pragma unroll
                for (int m = 1; m < 16; m <<= 1) dot += __shfl_xor(dot, m);
                const float mean = (st.x - sp) * (1.f / 128.f);
                const float var = fmaf(-2.f, dot, st.y + qp) * (1.f / 128.f) - mean * mean;
                const float r = rsqrtf(var + 1e-5f);
                rsum += r;
                cmsum = fmaf(mean, r, cmsum);
                #pragma unroll
                for (int q = 0; q < 8; ++q) a[q] = fmaf(xj[q], r, a[q]);
            }
            #pragma unroll
            for (int q = 0; q < 8; ++q) { a[q] += __shfl_xor(a[q], 16); a[q] += __shfl_xor(a[q], 32); }
            rsum += __shfl_xor(rsum, 16);  rsum += __shfl_xor(rsum, 32);
            cmsum += __shfl_xor(cmsum, 16); cmsum += __shfl_xor(cmsum, 32);
            if (quarter == 0) {
                ushort o8[8];
                if (deg > 0) {
                    const float inv = 1.f / (float)deg;
                    #pragma unroll
                    for (int q = 0; q < 8; ++q)
                        o8[q] = f2bf(fmaf((a[q] - pr[q] * rsum - cmsum) * inv, gv[q], bv[q]));
                } else {
                    #pragma unroll
                    for (int q = 0; q < 8; ++q) o8[q] = 0;
                }
                *reinterpret_cast<bf16x8*>(&Hs[swz128(nl_, c)]) = *reinterpret_cast<bf16x8*>(&o8[0]);
            }
        }
    }
    __syncthreads();

    // update GEMM: concat(x=As | agg=Hs) @ uwt + ub, K=256
    f32x4 acc[2][2] = {};
    for (int kb = 0; kb < 8; ++kb) {
        int k = kb * 32 + lg * 8;
        const ushort* Ab = (k < 128) ? As : Hs;
        int kl = k & 127;
        bf16x8 a0 = *reinterpret_cast<const bf16x8*>(&Ab[swz128(lr, kl)]);
        bf16x8 a1 = *reinterpret_cast<const bf16x8*>(&Ab[swz128(lr + 16, kl)]);
        bf16x8 b0 = *reinterpret_cast<const bf16x8*>(&uwt[(size_t)(w * 32 + lr) * 256 + k]);
        bf16x8 b1v = *reinterpret_cast<const bf16x8*>(&uwt[(size_t)(w * 32 + 16 + lr) * 256 + k]);
        acc[0][0] = MFMA16(a0, b0, acc[0][0]);
        acc[0][1] = MFMA16(a0, b1v, acc[0][1]);
        acc[1][0] = MFMA16(a1, b0, acc[1][0]);
        acc[1][1] = MFMA16(a1, b1v, acc[1][1]);
    }
    __syncthreads();   // all reads of As/Hs done before os overlays them

    {
        float bc[2] = { ub[w * 32 + lr], ub[w * 32 + 16 + lr] };
        #pragma unroll
        for (int mi = 0; mi < 2; ++mi)
            #pragma unroll
            for (int ni = 0; ni < 2; ++ni) {
                int col = w * 32 + ni * 16 + lr;
                #pragma unroll
                for (int j = 0; j < 4; ++j) {
                    int row = mi * 16 + lg * 4 + j;
                    os[row][col] = fmaxf(acc[mi][ni][j] + bc[ni], 0.f);
                }
            }
    }
    __syncthreads();

    // node LayerNorm + relu + stats (+head); 8 lanes/node, 16 channels/lane
    const int nl = w * 8 + (l >> 3);
    const int cl = l & 7;
    float vals[16];
    float sm = 0.f, sq = 0.f;
    #pragma unroll
    for (int t = 0; t < 16; ++t) {
        float u = os[nl][cl + 8 * t];
        vals[t] = u; sm += u; sq = fmaf(u, u, sq);
    }
    #pragma unroll
    for (int m = 1; m < 8; m <<= 1) { sm += __shfl_xor(sm, m); sq += __shfl_xor(sq, m); }
    float mean = sm * (1.f / 128.f);
    float var = sq * (1.f / 128.f) - mean * mean;
    float r = rsqrtf(var + 1e-5f);
    int node = base + nl;
    if (node < N) {
        float so = 0.f, sqo = 0.f, hsum = 0.f;
        bool doHead = (node < headS);
        #pragma unroll
        for (int t = 0; t < 16; ++t) {
            int cch = cl + 8 * t;
            float o = fmaxf(fmaf((vals[t] - mean) * r, ng[cch], nb[cch]), 0.f);
            ushort ob = f2bf(o);
            xout[(size_t)node * CC + cch] = ob;
            float orr = bf2f(ob);
            so += orr; sqo = fmaf(orr, orr, sqo);
            if (doHead) hsum = fmaf(o, hw[cch], hsum);
        }
        #pragma unroll
        for (int m = 1; m < 8; m <<= 1) { so += __shfl_xor(so, m); sqo += __shfl_xor(sqo, m); }
        if (doHead) {
            #pragma unroll
            for (int m = 1; m < 8; m <<= 1) hsum += __shfl_xor(hsum, m);
            if (cl == 0) hout[node] = hsum + hb[0];
        }
        if (cl == 0) statOut[node] = make_float2(so, sqo);
    }
}

__global__ __launch_bounds__(256)
void k_layer_dual(
    const ushort* __restrict__ xb_c, const ushort* __restrict__ xa_c,
    const float2* __restrict__ stat_a_c, const float2* __restrict__ stat_b_c,
    const int* __restrict__ rowp_b, const int* __restrict__ srcs_ab,
    const int* __restrict__ rowp_a, const int* __restrict__ srcs_ba,
    ushort* __restrict__ xb_n, ushort* __restrict__ xa_n,
    float2* __restrict__ stat_b_n, float2* __restrict__ stat_a_n,
    int NB, int NA, int GB,
    const ushort* __restrict__ w1t0, const float* __restrict__ b10,
    const ushort* __restrict__ w2t0, const float* __restrict__ b20,
    const float* __restrict__ mg0, const float* __restrict__ mb0,
    const ushort* __restrict__ uwt0, const float* __restrict__ ub0,
    const float* __restrict__ ng0, const float* __restrict__ nb0,
    const ushort* __restrict__ w1t1, const float* __restrict__ b11,
    const ushort* __restrict__ w2t1, const float* __restrict__ b21,
    const float* __restrict__ mg1, const float* __restrict__ mb1,
    const ushort* __restrict__ uwt1, const float* __restrict__ ub1,
    const float* __restrict__ ng1, const float* __restrict__ nb1,
    const float* __restrict__ hw, const float* __restrict__ hb,
    float* __restrict__ hout, int headS)
{
    __shared__ __align__(16) char smem[25088];
    if ((int)blockIdx.x < GB)
        layer_body(smem, xb_c, xa_c, stat_a_c, rowp_b, srcs_ab,
                   w1t0, b10, w2t0, b20, mg0, mb0, uwt0, ub0, ng0, nb0,
                   xb_n, stat_b_n, NB, blockIdx.x, hw, hb, hout, 0);
    else
        layer_body(smem, xa_c, xb_c, stat_b_c, rowp_a, srcs_ba,
                   w1t1, b11, w2t1, b21, mg1, mb1, uwt1, ub1, ng1, nb1,
                   xa_n, stat_a_n, NA, blockIdx.x - GB, hw, hb, hout, headS);
}

extern "C" void kernel_launch(void* const* d_in, const int* in_sizes, int n_in,
                              void* d_out, int out_size, void* d_ws, size_t ws_size,
                              hipStream_t stream)
{
    const float* x_a_in = (const float*)d_in[0];
    const float* x_b_in = (const float*)d_in[1];
    const int*   e_ab   = (const int*)d_in[2];
    const int*   e_ba   = (const int*)d_in[3];
    const float* pw1    = (const float*)d_in[4];
    const float* pb1    = (const float*)d_in[5];
    const float* pw2    = (const float*)d_in[6];
    const float* pb2    = (const float*)d_in[7];
    const float* mgam   = (const float*)d_in[8];
    const float* mbet   = (const float*)d_in[9];
    const float* uw     = (const float*)d_in[10];
    const float* ubias  = (const float*)d_in[11];
    const float* ngam   = (const float*)d_in[12];
    const float* nbet   = (const float*)d_in[13];
    const float* hw     = (const float*)d_in[14];
    const float* hb     = (const float*)d_in[15];

    const int NA  = in_sizes[0] / CC;
    const int NB  = in_sizes[1] / CC;
    const int Eab = in_sizes[2] / 2;
    const int Eba = in_sizes[3] / 2;

    float* ws = (float*)d_ws;
    size_t off = 0;  // in floats
    ushort* xa0 = (ushort*)(ws + off); off += (size_t)NA * CC / 2;
    ushort* xa1 = (ushort*)(ws + off); off += (size_t)NA * CC / 2;
    ushort* xb0 = (ushort*)(ws + off); off += (size_t)NB * CC / 2;
    ushort* xb1 = (ushort*)(ws + off); off += (size_t)NB * CC / 2;
    float2* sa0 = (float2*)(ws + off); off += (size_t)NA * 2;
    float2* sa1 = (float2*)(ws + off); off += (size_t)NA * 2;
    float2* sb0 = (float2*)(ws + off); off += (size_t)NB * 2;
    float2* sb1 = (float2*)(ws + off); off += (size_t)NB * 2;
    ushort* w1t = (ushort*)(ws + off); off += 4 * 16384 / 2;
    ushort* w2t = (ushort*)(ws + off); off += 4 * 16384 / 2;
    ushort* uwt = (ushort*)(ws + off); off += 4 * 32768 / 2;
    int* iw = (int*)(ws + off);
    size_t ioff = 0;
    int* cnt_b   = iw + ioff; ioff += NB;
    int* cnt_a   = iw + ioff; ioff += NA;
    int* rowp_b  = iw + ioff; ioff += NB + 1;
    int* rowp_a  = iw + ioff; ioff += NA + 1;
    int* off_b   = iw + ioff; ioff += NB;
    int* off_a   = iw + ioff; ioff += NA;
    int* srcs_ab = iw + ioff; ioff += Eab;
    int* srcs_ba = iw + ioff; ioff += Eba;

    const int GB = (NB + 31) / 32, GA = (NA + 31) / 32;

    k_init_dual<<<dim3((NA + NB + 7) / 8), dim3(256), 0, stream>>>(
        x_a_in, xa0, sa0, NA, x_b_in, xb0, sb0, NB);

    k_wcvt<<<dim3(1024), dim3(256), 0, stream>>>(pw1, pw2, uw, w1t, w2t, uwt);

    hipMemsetAsync(cnt_b, 0, (size_t)(NB + NA) * sizeof(int), stream);
    k_hist_dual<<<dim3((Eab + Eba + 255) / 256), dim3(256), 0, stream>>>(
        e_ab + Eab, Eab, cnt_b, e_ba + Eba, Eba, cnt_a);
    k_scan_dual<<<dim3(2), dim3(SCAN_T), 0, stream>>>(
        cnt_b, rowp_b, off_b, NB, cnt_a, rowp_a, off_a, NA);
    k_scatter_dual<<<dim3((Eab + Eba + 255) / 256), dim3(256), 0, stream>>>(
        e_ab, e_ab + Eab, Eab, off_b, srcs_ab,
        e_ba, e_ba + Eba, Eba, off_a, srcs_ba);

    ushort* xac = xa0; ushort* xan = xa1;
    ushort* xbc = xb0; ushort* xbn = xb1;
    float2* sac = sa0; float2* san = sa1;
    float2* sbc = sb0; float2* sbn = sb1;

    for (int lyr = 0; lyr < 2; ++lyr) {
        int t0 = lyr * 2 + 0;   // conv a->b (dst = b)
        int t1 = lyr * 2 + 1;   // conv b->a (dst = a)
        int headS = (lyr == 1) ? out_size : 0;

        k_layer_dual<<<dim3(GB + GA), dim3(256), 0, stream>>>(
            xbc, xac, sac, sbc,
            rowp_b, srcs_ab, rowp_a, srcs_ba,
            xbn, xan, sbn, san,
            NB, NA, GB,
            w1t + (size_t)t0 * 16384, pb1 + t0 * CC, w2t + (size_t)t0 * 16384, pb2 + t0 * CC,
            mgam + t0 * CC, mbet + t0 * CC,
            uwt + (size_t)t0 * 32768, ubias + t0 * CC, ngam + t0 * CC, nbet + t0 * CC,
            w1t + (size_t)t1 * 16384, pb1 + t1 * CC, w2t + (size_t)t1 * 16384, pb2 + t1 * CC,
            mgam + t1 * CC, mbet + t1 * CC,
            uwt + (size_t)t1 * 32768, ubias + t1 * CC, ngam + t1 * CC, nbet + t1 * CC,
            hw, hb, (float*)d_out, headS);

        ushort* t;
        t = xac; xac = xan; xan = t;
        t = xbc; xbc = xbn; xbn = t;
        float2* s;
        s = sac; sac = san; san = s;
        s = sbc; sbc = sbn; sbn = s;
    }
}